// Round 7
// baseline (757.841 us; speedup 1.0000x reference)
//
#include <hip/hip_runtime.h>
#include <hip/hip_bf16.h>
#include <math.h>

#define NS 1024
#define ST 32
#define DF 158
#define DM 256
#define KE 192                 // embed K padded to BK=64 multiple
#define ROWS (NS*ST)           // 32768
#define SZ ((size_t)ROWS*DM)   // 8388608 elems
#define LN_EPS 1e-5f
#define LOG2E 1.44269504088896f

typedef __attribute__((ext_vector_type(8)))  __bf16 bf16x8;
typedef __attribute__((ext_vector_type(16))) float  f32x16;

__device__ __forceinline__ float wave_sum(float v) {
#pragma unroll
    for (int o = 32; o > 0; o >>= 1) v += __shfl_xor(v, o);
    return v;
}

__device__ __forceinline__ unsigned pkbf(float a, float b) {
    __hip_bfloat16 ha = __float2bfloat16(a), hb = __float2bfloat16(b);
    unsigned short ua, ub;
    __builtin_memcpy(&ua, &ha, 2); __builtin_memcpy(&ub, &hb, 2);
    return (unsigned)ua | ((unsigned)ub << 16);
}

// ================= conversion kernels (run every launch; idempotent) =========
__global__ __launch_bounds__(256) void cvtx_k(const float* __restrict__ x,
        __hip_bfloat16* __restrict__ xb) {
    int idx = blockIdx.x*256 + threadIdx.x;          // < 32768*192
    int r = idx / KE, c = idx - r*KE;
    float v = (c < DF) ? x[(size_t)r*DF + c] : 0.f;
    xb[idx] = __float2bfloat16(v);
}

struct WPack { const float* s[11]; __hip_bfloat16* d[11]; };

__global__ __launch_bounds__(256) void cvtw_k(WPack wp) {
    const float* W = wp.s[blockIdx.z];
    __hip_bfloat16* Wt = wp.d[blockIdx.z];
    __shared__ float t[64][65];
    int bi = blockIdx.x*64, bj = blockIdx.y*64;
    int r = threadIdx.x >> 2, c0 = (threadIdx.x & 3) * 16;
#pragma unroll
    for (int i = 0; i < 16; i += 4) {
        float4 v = *(const float4*)(W + (size_t)(bi + r)*DM + bj + c0 + i);
        t[r][c0+i+0] = v.x; t[r][c0+i+1] = v.y;
        t[r][c0+i+2] = v.z; t[r][c0+i+3] = v.w;
    }
    __syncthreads();
    unsigned u[8];
#pragma unroll
    for (int i = 0; i < 8; ++i) u[i] = pkbf(t[c0+2*i][r], t[c0+2*i+1][r]);
    __hip_bfloat16* op = Wt + (size_t)(bj + r)*DM + bi + c0;
    *(uint4*)(op)     = make_uint4(u[0], u[1], u[2], u[3]);
    *(uint4*)(op + 8) = make_uint4(u[4], u[5], u[6], u[7]);
}

__global__ __launch_bounds__(192) void cvte_k(const float* __restrict__ W,
        __hip_bfloat16* __restrict__ Wt) {
    int n = blockIdx.x, t = threadIdx.x;   // t < 192
    float v = (t < DF) ? W[(size_t)t*DM + n] : 0.f;
    Wt[(size_t)n*KE + t] = __float2bfloat16(v);
}

// ================= LayerNorm: one wave per row, no barriers ==================
__global__ __launch_bounds__(256) void ln_k(const float* __restrict__ a,
        const float* __restrict__ g, const float* __restrict__ be,
        float* __restrict__ out, __hip_bfloat16* __restrict__ outb) {
    int w = threadIdx.x >> 6, lane = threadIdx.x & 63;
    size_t r = (size_t)blockIdx.x*4 + w;
    const float* ar = a + r*DM + lane*4;
    float4 v = *(const float4*)(ar);
    float mu = wave_sum(v.x+v.y+v.z+v.w) * (1.0f/DM);
    float4 c = make_float4(v.x-mu, v.y-mu, v.z-mu, v.w-mu);
    float var = wave_sum(c.x*c.x + c.y*c.y + c.z*c.z + c.w*c.w) * (1.0f/DM);
    float rs = rsqrtf(var + LN_EPS);
    float4 g4 = *(const float4*)(g + lane*4);
    float4 b4 = *(const float4*)(be + lane*4);
    float4 o = make_float4(c.x*rs*g4.x + b4.x, c.y*rs*g4.y + b4.y,
                           c.z*rs*g4.z + b4.z, c.w*rs*g4.w + b4.w);
    *(float4*)(out + r*DM + lane*4) = o;
    *(uint2*)(outb + r*DM + lane*4) = make_uint2(pkbf(o.x, o.y), pkbf(o.z, o.w));
}

// ================= MFMA GEMM: C[M,N] = A[M,K]@W[K,N] =========================
// fmt: 0 = std [row][col]; 1 = sfmt [(t*4+h)][stock][d]; 2 = tfmt [h][stock][t][d]
// fused: colg>>8 selects output segment (Cb + seg*SZ); scale applies to seg 0 only.
__global__ __launch_bounds__(256) void mgemm_k(const __hip_bfloat16* __restrict__ A,
        int sA, int nk, const __hip_bfloat16* __restrict__ Wt, int sW,
        const float* __restrict__ bias, const float* __restrict__ pe,
        const float* __restrict__ resid, float* __restrict__ Cf,
        __hip_bfloat16* __restrict__ Cb, int relu, int fmt, float scale, int fused) {
    __shared__ __hip_bfloat16 As[128*72];
    __shared__ __hip_bfloat16 Ws[128*72];
    const int tid = threadIdx.x;
    const int w = tid >> 6, lane = tid & 63;
    const int uh = lane >> 5, l31 = lane & 31;
    const int wm = (w >> 1)*64, wn = (w & 1)*64;
    const size_t m0 = (size_t)blockIdx.x*128;
    const int n0 = blockIdx.y*128;

    f32x16 acc[2][2];
#pragma unroll
    for (int mt = 0; mt < 2; ++mt)
#pragma unroll
        for (int nt = 0; nt < 2; ++nt)
#pragma unroll
            for (int r = 0; r < 16; ++r) acc[mt][nt][r] = 0.f;

    // staging: 128 rows x 64 k per matrix; thread stages 32 cols of one row
    const int lr = tid >> 1, lcb = (tid & 1)*32;
    const __hip_bfloat16* ap = A  + (m0 + lr)*sA + lcb;
    const __hip_bfloat16* wp = Wt + (size_t)(n0 + lr)*sW + lcb;
    uint4 pa0 = *(const uint4*)(ap),      pa1 = *(const uint4*)(ap + 8);
    uint4 pa2 = *(const uint4*)(ap + 16), pa3 = *(const uint4*)(ap + 24);
    uint4 pw0 = *(const uint4*)(wp),      pw1 = *(const uint4*)(wp + 8);
    uint4 pw2 = *(const uint4*)(wp + 16), pw3 = *(const uint4*)(wp + 24);
    for (int kt = 0; kt < nk; ++kt) {
        __syncthreads();
        *(uint4*)&As[lr*72 + lcb]      = pa0;
        *(uint4*)&As[lr*72 + lcb + 8]  = pa1;
        *(uint4*)&As[lr*72 + lcb + 16] = pa2;
        *(uint4*)&As[lr*72 + lcb + 24] = pa3;
        *(uint4*)&Ws[lr*72 + lcb]      = pw0;
        *(uint4*)&Ws[lr*72 + lcb + 8]  = pw1;
        *(uint4*)&Ws[lr*72 + lcb + 16] = pw2;
        *(uint4*)&Ws[lr*72 + lcb + 24] = pw3;
        __syncthreads();
        if (kt + 1 < nk) {
            int ko = (kt + 1)*64;
            pa0 = *(const uint4*)(ap + ko);      pa1 = *(const uint4*)(ap + ko + 8);
            pa2 = *(const uint4*)(ap + ko + 16); pa3 = *(const uint4*)(ap + ko + 24);
            pw0 = *(const uint4*)(wp + ko);      pw1 = *(const uint4*)(wp + ko + 8);
            pw2 = *(const uint4*)(wp + ko + 16); pw3 = *(const uint4*)(wp + ko + 24);
        }
#pragma unroll
        for (int ks = 0; ks < 4; ++ks) {
            bf16x8 a0 = *(const bf16x8*)&As[(wm + l31)*72      + ks*16 + uh*8];
            bf16x8 a1 = *(const bf16x8*)&As[(wm + 32 + l31)*72 + ks*16 + uh*8];
            bf16x8 b0 = *(const bf16x8*)&Ws[(wn + l31)*72      + ks*16 + uh*8];
            bf16x8 b1 = *(const bf16x8*)&Ws[(wn + 32 + l31)*72 + ks*16 + uh*8];
            acc[0][0] = __builtin_amdgcn_mfma_f32_32x32x16_bf16(a0, b0, acc[0][0], 0, 0, 0);
            acc[0][1] = __builtin_amdgcn_mfma_f32_32x32x16_bf16(a0, b1, acc[0][1], 0, 0, 0);
            acc[1][0] = __builtin_amdgcn_mfma_f32_32x32x16_bf16(a1, b0, acc[1][0], 0, 0, 0);
            acc[1][1] = __builtin_amdgcn_mfma_f32_32x32x16_bf16(a1, b1, acc[1][1], 0, 0, 0);
        }
    }

#pragma unroll
    for (int nt = 0; nt < 2; ++nt) {
        int colg = n0 + wn + nt*32 + l31;
        int seg = fused ? (colg >> 8) : 0;
        int c8  = fused ? (colg & 255) : colg;
        float sc = (seg == 0) ? scale : 1.0f;
        float bz = bias ? bias[c8] : 0.f;
        __hip_bfloat16* cb = Cb ? (Cb + (size_t)seg*SZ) : (Cb);
#pragma unroll
        for (int mt = 0; mt < 2; ++mt) {
#pragma unroll
            for (int r = 0; r < 16; ++r) {
                size_t mg = m0 + wm + mt*32 + (r & 3) + ((r >> 2) << 3) + 4*uh;
                float v = (acc[mt][nt][r] + bz) * sc;
                if (pe)    v += pe[(mg & 31)*DM + c8];
                if (relu)  v = fmaxf(v, 0.f);
                if (resid) v += resid[mg*DM + c8];
                size_t oidx;
                if (fmt == 1)
                    oidx = (size_t)((mg & 31)*4 + (c8 >> 6))*65536 + (mg >> 5)*64 + (c8 & 63);
                else if (fmt == 2)
                    oidx = ((size_t)(c8 >> 6)*NS + (mg >> 5))*2048 + (mg & 31)*64 + (c8 & 63);
                else
                    oidx = mg*DM + c8;
                if (Cf) Cf[oidx] = v;
                if (cb) cb[oidx] = __float2bfloat16(v);
            }
        }
    }
}

// ================= T-attention: MFMA, one wave per head, tfmt QKV ============
union __align__(16) WLds { __hip_bfloat16 vt[64*40]; float ob[32*68]; };

__global__ __launch_bounds__(256) void attnT_k(const __hip_bfloat16* __restrict__ Q,
        const __hip_bfloat16* __restrict__ K, const __hip_bfloat16* __restrict__ V,
        float* __restrict__ O) {
    __shared__ WLds sm4[4];
    const int n = blockIdx.x;
    const int w = threadIdx.x >> 6, lane = threadIdx.x & 63;
    const int uh = lane >> 5, l31 = lane & 31;
    const size_t base = ((size_t)w*NS + n)*2048;   // head w, stock n

    bf16x8 kf[4], qf[4];
#pragma unroll
    for (int s = 0; s < 4; ++s) {
        kf[s] = *(const bf16x8*)(K + base + l31*64 + s*16 + uh*8);
        qf[s] = *(const bf16x8*)(Q + base + l31*64 + s*16 + uh*8);
    }
    __hip_bfloat16* vt = sm4[w].vt;
#pragma unroll
    for (int i = 0; i < 2; ++i) {
        int c = lane*2 + i;
        int dg = c >> 3, tg = c & 7;
        const ushort* vp = (const ushort*)(V + base + (tg*4)*64 + dg*4);
        ushort4 s0 = *(const ushort4*)(vp);
        ushort4 s1 = *(const ushort4*)(vp + 64);
        ushort4 s2 = *(const ushort4*)(vp + 128);
        ushort4 s3 = *(const ushort4*)(vp + 192);
        *(uint2*)&vt[(dg*4+0)*40 + tg*4] = make_uint2((unsigned)s0.x | ((unsigned)s1.x<<16),
                                                      (unsigned)s2.x | ((unsigned)s3.x<<16));
        *(uint2*)&vt[(dg*4+1)*40 + tg*4] = make_uint2((unsigned)s0.y | ((unsigned)s1.y<<16),
                                                      (unsigned)s2.y | ((unsigned)s3.y<<16));
        *(uint2*)&vt[(dg*4+2)*40 + tg*4] = make_uint2((unsigned)s0.z | ((unsigned)s1.z<<16),
                                                      (unsigned)s2.z | ((unsigned)s3.z<<16));
        *(uint2*)&vt[(dg*4+3)*40 + tg*4] = make_uint2((unsigned)s0.w | ((unsigned)s1.w<<16),
                                                      (unsigned)s2.w | ((unsigned)s3.w<<16));
    }

    f32x16 sa;
#pragma unroll
    for (int r = 0; r < 16; ++r) sa[r] = 0.f;
    sa = __builtin_amdgcn_mfma_f32_32x32x16_bf16(kf[0], qf[0], sa, 0, 0, 0);
    sa = __builtin_amdgcn_mfma_f32_32x32x16_bf16(kf[1], qf[1], sa, 0, 0, 0);
    sa = __builtin_amdgcn_mfma_f32_32x32x16_bf16(kf[2], qf[2], sa, 0, 0, 0);
    sa = __builtin_amdgcn_mfma_f32_32x32x16_bf16(kf[3], qf[3], sa, 0, 0, 0);

    float p[16], l = 0.f;
#pragma unroll
    for (int r = 0; r < 16; ++r) { p[r] = exp2f(sa[r]); l += p[r]; }
    l += __shfl_xor(l, 32);

    bf16x8 pf[2];
#pragma unroll
    for (int s = 0; s < 2; ++s) {
        unsigned A0 = pkbf(p[8*s+0], p[8*s+1]);
        unsigned A1 = pkbf(p[8*s+2], p[8*s+3]);
        unsigned B0 = pkbf(p[8*s+4], p[8*s+5]);
        unsigned B1 = pkbf(p[8*s+6], p[8*s+7]);
        unsigned xA0 = (unsigned)__shfl_xor((int)A0, 32);
        unsigned xA1 = (unsigned)__shfl_xor((int)A1, 32);
        unsigned xB0 = (unsigned)__shfl_xor((int)B0, 32);
        unsigned xB1 = (unsigned)__shfl_xor((int)B1, 32);
        union { uint4 i; bf16x8 v; } cv;
        cv.i = make_uint4(uh ? xB0 : A0, uh ? xB1 : A1,
                          uh ? B0 : xA0, uh ? B1 : xA1);
        pf[s] = cv.v;
    }

    f32x16 oa[2];
#pragma unroll
    for (int c = 0; c < 2; ++c) {
#pragma unroll
        for (int r = 0; r < 16; ++r) oa[c][r] = 0.f;
        bf16x8 v0 = *(const bf16x8*)&vt[(c*32 + l31)*40 + uh*8];
        bf16x8 v1 = *(const bf16x8*)&vt[(c*32 + l31)*40 + 16 + uh*8];
        oa[c] = __builtin_amdgcn_mfma_f32_32x32x16_bf16(v0, pf[0], oa[c], 0, 0, 0);
        oa[c] = __builtin_amdgcn_mfma_f32_32x32x16_bf16(v1, pf[1], oa[c], 0, 0, 0);
    }

    float invl = 1.0f / l;
    float* ob = sm4[w].ob;
#pragma unroll
    for (int c = 0; c < 2; ++c)
#pragma unroll
        for (int r = 0; r < 16; ++r) {
            int d = (r & 3) + ((r >> 2) << 3) + 4*uh + 32*c;
            ob[l31*68 + d] = oa[c][r] * invl;
        }
    int t = lane >> 1, d0 = (lane & 1)*32;
    float* gp = O + ((size_t)n*ST + t)*DM + w*64 + d0;
#pragma unroll
    for (int i = 0; i < 8; ++i) {
        float4 prev = *(const float4*)(gp + 4*i);
        float4 nv = *(const float4*)&ob[t*68 + d0 + 4*i];
        *(float4*)(gp + 4*i) = make_float4(prev.x+nv.x, prev.y+nv.y, prev.z+nv.z, prev.w+nv.w);
    }
}

// ================= S-attention: MFMA flash, sfmt QKV, XCD-swizzled ===========
// grid (tt, h, qt): blocks sharing a (tt,h) K/V slice differ by 128 in linear
// id (multiple of 8) -> same XCD -> slice fetched from HBM once.
// Each block: 256 q rows = 2 strips of 128; K/Vt staged once per kt, used twice.
union __align__(16) LdsS {
    struct { __hip_bfloat16 K[64*72]; __hip_bfloat16 Vt[64*72]; } s;
    float Ob[4][32*68];
};

__global__ __launch_bounds__(256) void attnS_k(const __hip_bfloat16* __restrict__ Qb,
        const __hip_bfloat16* __restrict__ Kb, const __hip_bfloat16* __restrict__ Vb,
        float* __restrict__ O) {
    __shared__ LdsS sm;
    const int tt = blockIdx.x, h = blockIdx.y, qt = blockIdx.z;
    const int tid = threadIdx.x;
    const int w = tid >> 6, lane = tid & 63;
    const int uh = lane >> 5, l31 = lane & 31;
    const size_t hb = (size_t)(tt*4 + h)*65536;   // sfmt slice base

    // Q^T B-fragments for both strips straight from global
    bf16x8 qf[2][4];
#pragma unroll
    for (int s = 0; s < 2; ++s) {
        const __hip_bfloat16* qp = Qb + hb + (size_t)(qt*256 + s*128 + w*32 + l31)*64 + 8*uh;
        qf[s][0] = *(const bf16x8*)(qp);
        qf[s][1] = *(const bf16x8*)(qp + 16);
        qf[s][2] = *(const bf16x8*)(qp + 32);
        qf[s][3] = *(const bf16x8*)(qp + 48);
    }

    f32x16 oa[2][2];
#pragma unroll
    for (int s = 0; s < 2; ++s)
#pragma unroll
        for (int c = 0; c < 2; ++c)
#pragma unroll
            for (int r = 0; r < 16; ++r) oa[s][c][r] = 0.f;
    float lrun[2] = {0.f, 0.f};

    for (int kt = 0; kt < 16; ++kt) {
        __syncthreads();
        // stage K row-major (8 KB contiguous tile)
        {
            const __hip_bfloat16* kb = Kb + hb + (size_t)kt*4096;
#pragma unroll
            for (int i = 0; i < 2; ++i) {
                int c = tid*2 + i;
                int j = c >> 3, col = (c & 7)*8;
                *(uint4*)&sm.s.K[j*72 + col] = *(const uint4*)(kb + c*8);
            }
        }
        // stage V transposed
        {
            int j0 = (tid & 15)*4, cb = (tid >> 4)*4;
            const ushort* vp = (const ushort*)(Vb + hb + (size_t)(kt*64 + j0)*64 + cb);
            ushort4 s0 = *(const ushort4*)(vp);
            ushort4 s1 = *(const ushort4*)(vp + 64);
            ushort4 s2 = *(const ushort4*)(vp + 128);
            ushort4 s3 = *(const ushort4*)(vp + 192);
            *(uint2*)&sm.s.Vt[(cb+0)*72 + j0] = make_uint2((unsigned)s0.x | ((unsigned)s1.x<<16),
                                                           (unsigned)s2.x | ((unsigned)s3.x<<16));
            *(uint2*)&sm.s.Vt[(cb+1)*72 + j0] = make_uint2((unsigned)s0.y | ((unsigned)s1.y<<16),
                                                           (unsigned)s2.y | ((unsigned)s3.y<<16));
            *(uint2*)&sm.s.Vt[(cb+2)*72 + j0] = make_uint2((unsigned)s0.z | ((unsigned)s1.z<<16),
                                                           (unsigned)s2.z | ((unsigned)s3.z<<16));
            *(uint2*)&sm.s.Vt[(cb+3)*72 + j0] = make_uint2((unsigned)s0.w | ((unsigned)s1.w<<16),
                                                           (unsigned)s2.w | ((unsigned)s3.w<<16));
        }
        __syncthreads();

#pragma unroll
        for (int s = 0; s < 2; ++s) {
            // S^T = K * Q^T : 2 x (32x32), chained over hd=64 (Q pre-scaled)
            f32x16 sa[2];
#pragma unroll
            for (int ct = 0; ct < 2; ++ct) {
                f32x16 a2;
#pragma unroll
                for (int r = 0; r < 16; ++r) a2[r] = 0.f;
                const __hip_bfloat16* kb = &sm.s.K[(ct*32 + l31)*72 + 8*uh];
                a2 = __builtin_amdgcn_mfma_f32_32x32x16_bf16(*(const bf16x8*)(kb +  0), qf[s][0], a2, 0, 0, 0);
                a2 = __builtin_amdgcn_mfma_f32_32x32x16_bf16(*(const bf16x8*)(kb + 16), qf[s][1], a2, 0, 0, 0);
                a2 = __builtin_amdgcn_mfma_f32_32x32x16_bf16(*(const bf16x8*)(kb + 32), qf[s][2], a2, 0, 0, 0);
                a2 = __builtin_amdgcn_mfma_f32_32x32x16_bf16(*(const bf16x8*)(kb + 48), qf[s][3], a2, 0, 0, 0);
                sa[ct] = a2;
            }

            // no-max softmax accumulation: p = exp2(score'), l += sum
            float p[32];
            float rs = 0.f;
#pragma unroll
            for (int ct = 0; ct < 2; ++ct)
#pragma unroll
                for (int r = 0; r < 16; ++r) {
                    float e = exp2f(sa[ct][r]);
                    p[ct*16 + r] = e;
                    rs += e;
                }
            rs += __shfl_xor(rs, 32);
            lrun[s] += rs;

            // P^T B-fragments from registers + xor-32 shuffles
            bf16x8 bfr[4];
#pragma unroll
            for (int q = 0; q < 4; ++q) {
                int ct = q >> 1, b = (q & 1) << 3;
                unsigned A0 = pkbf(p[ct*16+b+0], p[ct*16+b+1]);
                unsigned A1 = pkbf(p[ct*16+b+2], p[ct*16+b+3]);
                unsigned B0 = pkbf(p[ct*16+b+4], p[ct*16+b+5]);
                unsigned B1 = pkbf(p[ct*16+b+6], p[ct*16+b+7]);
                unsigned xA0 = (unsigned)__shfl_xor((int)A0, 32);
                unsigned xA1 = (unsigned)__shfl_xor((int)A1, 32);
                unsigned xB0 = (unsigned)__shfl_xor((int)B0, 32);
                unsigned xB1 = (unsigned)__shfl_xor((int)B1, 32);
                union { uint4 i; bf16x8 v; } cv;
                cv.i = make_uint4(uh ? xB0 : A0, uh ? xB1 : A1,
                                  uh ? B0 : xA0, uh ? B1 : xA1);
                bfr[q] = cv.v;
            }

            // O^T += V^T * P^T
#pragma unroll
            for (int c = 0; c < 2; ++c) {
                const __hip_bfloat16* vb = &sm.s.Vt[(c*32 + l31)*72 + 8*uh];
                oa[s][c] = __builtin_amdgcn_mfma_f32_32x32x16_bf16(*(const bf16x8*)(vb +  0), bfr[0], oa[s][c], 0, 0, 0);
                oa[s][c] = __builtin_amdgcn_mfma_f32_32x32x16_bf16(*(const bf16x8*)(vb + 16), bfr[1], oa[s][c], 0, 0, 0);
                oa[s][c] = __builtin_amdgcn_mfma_f32_32x32x16_bf16(*(const bf16x8*)(vb + 32), bfr[2], oa[s][c], 0, 0, 0);
                oa[s][c] = __builtin_amdgcn_mfma_f32_32x32x16_bf16(*(const bf16x8*)(vb + 48), bfr[3], oa[s][c], 0, 0, 0);
            }
        }
    }

    // epilogue: per strip, transpose O^T via wave-local LDS, fused resid RMW
    __syncthreads();
    float* ob = sm.Ob[w];
#pragma unroll
    for (int s = 0; s < 2; ++s) {
        float invl = 1.0f / lrun[s];
#pragma unroll
        for (int c = 0; c < 2; ++c)
#pragma unroll
            for (int r = 0; r < 16; ++r) {
                int d = (r & 3) + ((r >> 2) << 3) + 4*uh + 32*c;
                ob[l31*68 + d] = oa[s][c][r] * invl;
            }
#pragma unroll
        for (int pp = 0; pp < 2; ++pp) {
            int qr = pp*16 + (lane >> 2);
            int dc = (lane & 3) << 4;
            float* gp = O + ((size_t)(qt*256 + s*128 + w*32 + qr)*ST + tt)*DM + h*64 + dc;
#pragma unroll
            for (int i = 0; i < 4; ++i) {
                float4 prev = *(const float4*)(gp + 4*i);
                float4 nv = *(const float4*)&ob[qr*68 + dc + 4*i];
                *(float4*)(gp + 4*i) = make_float4(prev.x+nv.x, prev.y+nv.y,
                                                   prev.z+nv.z, prev.w+nv.w);
            }
        }
    }
}

// ================= temporal pooling + decoder ================================
__global__ __launch_bounds__(256) void final_k(const float* __restrict__ H,
        const float* __restrict__ HH, const float* __restrict__ dw,
        const float* __restrict__ db, float* __restrict__ out) {
    int n = blockIdx.x, d = threadIdx.x;
    int w = d >> 6, lane = d & 63;
    __shared__ float lam[ST];
    __shared__ float red[8];
    const float* hh = HH + (size_t)n*ST*DM;
    float4 qd = *(const float4*)(hh + 31*DM + lane*4);
#pragma unroll
    for (int i = 0; i < 8; ++i) {
        int t = w*8 + i;
        float4 h4 = *(const float4*)(hh + t*DM + lane*4);
        float s = wave_sum(h4.x*qd.x + h4.y*qd.y + h4.z*qd.z + h4.w*qd.w);
        if (lane == 0) lam[t] = s;
    }
    __syncthreads();
    float mx = -1e30f;
#pragma unroll
    for (int t = 0; t < ST; ++t) mx = fmaxf(mx, lam[t]);
    float sum = 0.f;
#pragma unroll
    for (int t = 0; t < ST; ++t) sum += __expf(lam[t]-mx);
    float acc = 0.f;
    const float* hrow = H + (size_t)n*ST*DM;
#pragma unroll
    for (int t = 0; t < ST; ++t) acc += __expf(lam[t]-mx) * hrow[t*DM + d];
    acc /= sum;
    float p0 = wave_sum(acc * dw[2*d+0]);
    float p1 = wave_sum(acc * dw[2*d+1]);
    if (lane == 0) { red[w] = p0; red[4 + w] = p1; }
    __syncthreads();
    if (d == 0) {
        float r0 = red[0]+red[1]+red[2]+red[3] + db[0];
        float r1 = red[4]+red[5]+red[6]+red[7] + db[1];
        out[(size_t)n*2+0] = r0;           out[(size_t)n*2+1] = r1;
        out[2048 + (size_t)n*2+0] = r0;    out[2048 + (size_t)n*2+1] = r1;
        out[4096 + (size_t)n*2+0] = r0;    out[4096 + (size_t)n*2+1] = r1;
        if (n == 0) out[6144] = 0.f;
    }
}

extern "C" void kernel_launch(void* const* d_in, const int* in_sizes, int n_in,
                              void* d_out, int out_size, void* d_ws, size_t ws_size,
                              hipStream_t stream) {
    const float* x     = (const float*)d_in[0];
    const float* emb_w = (const float*)d_in[5];
    const float* emb_b = (const float*)d_in[6];
    const float* pe    = (const float*)d_in[7];
    const float* t_g1  = (const float*)d_in[11];
    const float* t_b1  = (const float*)d_in[12];
    const float* t_g2  = (const float*)d_in[13];
    const float* t_b2  = (const float*)d_in[14];
    const float* t_bb1 = (const float*)d_in[16];
    const float* t_bb2 = (const float*)d_in[18];
    const float* s_g1  = (const float*)d_in[22];
    const float* s_b1  = (const float*)d_in[23];
    const float* s_g2  = (const float*)d_in[24];
    const float* s_b2  = (const float*)d_in[25];
    const float* s_bb1 = (const float*)d_in[27];
    const float* s_bb2 = (const float*)d_in[29];
    const float* dec_w = (const float*)d_in[31];
    const float* dec_b = (const float*)d_in[32];
    float* out = (float*)d_out;

    // ---- workspace layout (~143 MB) ----
    float* F0 = (float*)d_ws;                       // 32 MB
    float* F1 = F0 + SZ;                            // 32 MB
    __hip_bfloat16* H0 = (__hip_bfloat16*)(F1 + SZ);// 16 MB each
    __hip_bfloat16* H1 = H0 + SZ;                   // H1,H2,H3 contiguous (fused QKV)
    __hip_bfloat16* H2 = H1 + SZ;
    __hip_bfloat16* H3 = H2 + SZ;
    __hip_bfloat16* WT  = H3 + SZ;                  // 11 x 256x256
    __hip_bfloat16* WTE = WT + (size_t)11*DM*DM;    // 256x192
    __hip_bfloat16* XB  = WTE + (size_t)DM*KE;      // 32768x192

    // ---- conversions ----
    cvtx_k<<<ROWS*KE/256, 256, 0, stream>>>(x, XB);
    WPack wp;
    const int widx[11] = {8, 9, 10, 15, 17, 19, 20, 21, 26, 28, 30};
    for (int i = 0; i < 11; ++i) {
        wp.s[i] = (const float*)d_in[widx[i]];
        wp.d[i] = WT + (size_t)i*DM*DM;
    }
    cvtw_k<<<dim3(4, 4, 11), 256, 0, stream>>>(wp);
    cvte_k<<<DM, 192, 0, stream>>>(emb_w, WTE);

    dim3 gg(ROWS/128, 2);
    dim3 gq(ROWS/128, 6);                            // fused QKV: N = 768
    __hip_bfloat16* WqT = WT;                        // Wq|Wk|Wv contiguous
    __hip_bfloat16* W1  = WT + (size_t)3*DM*DM;
    __hip_bfloat16* W2  = WT + (size_t)4*DM*DM;
    __hip_bfloat16* SWq = WT + (size_t)5*DM*DM;      // SWq|SWk|SWv contiguous
    __hip_bfloat16* SW1 = WT + (size_t)8*DM*DM;
    __hip_bfloat16* SW2 = WT + (size_t)9*DM*DM;
    __hip_bfloat16* WTA = WT + (size_t)10*DM*DM;

    // ---- embed + PE (MFMA gemm, K=192 padded) ----
    mgemm_k<<<gg, 256, 0, stream>>>(XB, KE, 3, WTE, KE, emb_b, pe, nullptr, F0, nullptr, 0, 0, 1.f, 0);
    // ---- TAttention block ----
    ln_k<<<ROWS/4, 256, 0, stream>>>(F0, t_g1, t_b1, F1, H0);            // F1=xn, H0=xn(bf)
    mgemm_k<<<gq, 256, 0, stream>>>(H0, 256, 4, WqT, 256, nullptr, nullptr, nullptr, nullptr, H1, 0, 2, LOG2E, 1);
    attnT_k<<<NS, 256, 0, stream>>>(H1, H2, H3, F1);                     // F1 = xn+att
    ln_k<<<ROWS/4, 256, 0, stream>>>(F1, t_g2, t_b2, F0, H0);            // F0=xt, H0=xt(bf)
    mgemm_k<<<gg, 256, 0, stream>>>(H0, 256, 4, W1, 256, t_bb1, nullptr, nullptr, nullptr, H1, 1, 0, 1.f, 0);
    mgemm_k<<<gg, 256, 0, stream>>>(H1, 256, 4, W2, 256, t_bb2, nullptr, F0, F1, nullptr, 0, 0, 1.f, 0);   // F1 = h1
    // ---- SAttention block ----
    ln_k<<<ROWS/4, 256, 0, stream>>>(F1, s_g1, s_b1, F0, H0);            // F0=xn2, H0=xn2(bf)
    mgemm_k<<<gq, 256, 0, stream>>>(H0, 256, 4, SWq, 256, nullptr, nullptr, nullptr, nullptr, H1, 0, 1, 0.125f*LOG2E, 1);
    attnS_k<<<dim3(32, 4, 4), 256, 0, stream>>>(H1, H2, H3, F0);         // F0 = xn2+att
    ln_k<<<ROWS/4, 256, 0, stream>>>(F0, s_g2, s_b2, F1, H0);            // F1=xt2, H0=xt2(bf)
    mgemm_k<<<gg, 256, 0, stream>>>(H0, 256, 4, SW1, 256, s_bb1, nullptr, nullptr, nullptr, H1, 1, 0, 1.f, 0);
    mgemm_k<<<gg, 256, 0, stream>>>(H1, 256, 4, SW2, 256, s_bb2, nullptr, F1, F0, H2, 0, 0, 1.f, 0);       // F0=h2, H2=h2(bf)
    // ---- temporal attention + decoder ----
    mgemm_k<<<gg, 256, 0, stream>>>(H2, 256, 4, WTA, 256, nullptr, nullptr, nullptr, F1, nullptr, 0, 0, 1.f, 0);  // F1 = hh
    final_k<<<NS, 256, 0, stream>>>(F0, F1, dec_w, dec_b, out);
}

// Round 8
// 737.279 us; speedup vs baseline: 1.0279x; 1.0279x over previous
//
#include <hip/hip_runtime.h>
#include <hip/hip_bf16.h>
#include <math.h>

#define NS 1024
#define ST 32
#define DF 158
#define DM 256
#define KE 192                 // embed K padded to BK=64 multiple
#define ROWS (NS*ST)           // 32768
#define SZ ((size_t)ROWS*DM)   // 8388608 elems
#define LN_EPS 1e-5f
#define LOG2E 1.44269504088896f

typedef __attribute__((ext_vector_type(8)))  __bf16 bf16x8;
typedef __attribute__((ext_vector_type(16))) float  f32x16;

__device__ __forceinline__ float wave_sum(float v) {
#pragma unroll
    for (int o = 32; o > 0; o >>= 1) v += __shfl_xor(v, o);
    return v;
}

__device__ __forceinline__ unsigned pkbf(float a, float b) {
    __hip_bfloat16 ha = __float2bfloat16(a), hb = __float2bfloat16(b);
    unsigned short ua, ub;
    __builtin_memcpy(&ua, &ha, 2); __builtin_memcpy(&ub, &hb, 2);
    return (unsigned)ua | ((unsigned)ub << 16);
}

// ================= conversion kernels (run every launch; idempotent) =========
__global__ __launch_bounds__(256) void cvtx_k(const float* __restrict__ x,
        __hip_bfloat16* __restrict__ xb) {
    int idx = blockIdx.x*256 + threadIdx.x;          // < 32768*192
    int r = idx / KE, c = idx - r*KE;
    float v = (c < DF) ? x[(size_t)r*DF + c] : 0.f;
    xb[idx] = __float2bfloat16(v);
}

struct WPack { const float* s[11]; __hip_bfloat16* d[11]; };

__global__ __launch_bounds__(256) void cvtw_k(WPack wp) {
    const float* W = wp.s[blockIdx.z];
    __hip_bfloat16* Wt = wp.d[blockIdx.z];
    __shared__ float t[64][65];
    int bi = blockIdx.x*64, bj = blockIdx.y*64;
    int r = threadIdx.x >> 2, c0 = (threadIdx.x & 3) * 16;
#pragma unroll
    for (int i = 0; i < 16; i += 4) {
        float4 v = *(const float4*)(W + (size_t)(bi + r)*DM + bj + c0 + i);
        t[r][c0+i+0] = v.x; t[r][c0+i+1] = v.y;
        t[r][c0+i+2] = v.z; t[r][c0+i+3] = v.w;
    }
    __syncthreads();
    unsigned u[8];
#pragma unroll
    for (int i = 0; i < 8; ++i) u[i] = pkbf(t[c0+2*i][r], t[c0+2*i+1][r]);
    __hip_bfloat16* op = Wt + (size_t)(bj + r)*DM + bi + c0;
    *(uint4*)(op)     = make_uint4(u[0], u[1], u[2], u[3]);
    *(uint4*)(op + 8) = make_uint4(u[4], u[5], u[6], u[7]);
}

__global__ __launch_bounds__(192) void cvte_k(const float* __restrict__ W,
        __hip_bfloat16* __restrict__ Wt) {
    int n = blockIdx.x, t = threadIdx.x;   // t < 192
    float v = (t < DF) ? W[(size_t)t*DM + n] : 0.f;
    Wt[(size_t)n*KE + t] = __float2bfloat16(v);
}

// ================= LayerNorm: one wave per row, no barriers ==================
__global__ __launch_bounds__(256) void ln_k(const float* __restrict__ a,
        const float* __restrict__ g, const float* __restrict__ be,
        float* __restrict__ out, __hip_bfloat16* __restrict__ outb) {
    int w = threadIdx.x >> 6, lane = threadIdx.x & 63;
    size_t r = (size_t)blockIdx.x*4 + w;
    const float* ar = a + r*DM + lane*4;
    float4 v = *(const float4*)(ar);
    float mu = wave_sum(v.x+v.y+v.z+v.w) * (1.0f/DM);
    float4 c = make_float4(v.x-mu, v.y-mu, v.z-mu, v.w-mu);
    float var = wave_sum(c.x*c.x + c.y*c.y + c.z*c.z + c.w*c.w) * (1.0f/DM);
    float rs = rsqrtf(var + LN_EPS);
    float4 g4 = *(const float4*)(g + lane*4);
    float4 b4 = *(const float4*)(be + lane*4);
    float4 o = make_float4(c.x*rs*g4.x + b4.x, c.y*rs*g4.y + b4.y,
                           c.z*rs*g4.z + b4.z, c.w*rs*g4.w + b4.w);
    *(float4*)(out + r*DM + lane*4) = o;
    *(uint2*)(outb + r*DM + lane*4) = make_uint2(pkbf(o.x, o.y), pkbf(o.z, o.w));
}

// ================= MFMA GEMM: C[M,N] = A[M,K]@W[K,N] =========================
// fmt: 0 = std [row][col]; 1 = sfmt [(t*4+h)][stock][d]; 2 = tfmt [h][stock][t][d]
// fused: colg>>8 selects output segment (Cb + seg*SZ); scale applies to seg 0 only.
__global__ __launch_bounds__(256) void mgemm_k(const __hip_bfloat16* __restrict__ A,
        int sA, int nk, const __hip_bfloat16* __restrict__ Wt, int sW,
        const float* __restrict__ bias, const float* __restrict__ pe,
        const float* __restrict__ resid, float* __restrict__ Cf,
        __hip_bfloat16* __restrict__ Cb, int relu, int fmt, float scale, int fused) {
    __shared__ __hip_bfloat16 As[128*72];
    __shared__ __hip_bfloat16 Ws[128*72];
    const int tid = threadIdx.x;
    const int w = tid >> 6, lane = tid & 63;
    const int uh = lane >> 5, l31 = lane & 31;
    const int wm = (w >> 1)*64, wn = (w & 1)*64;
    const size_t m0 = (size_t)blockIdx.x*128;
    const int n0 = blockIdx.y*128;

    f32x16 acc[2][2];
#pragma unroll
    for (int mt = 0; mt < 2; ++mt)
#pragma unroll
        for (int nt = 0; nt < 2; ++nt)
#pragma unroll
            for (int r = 0; r < 16; ++r) acc[mt][nt][r] = 0.f;

    // staging: 128 rows x 64 k per matrix; thread stages 32 cols of one row
    const int lr = tid >> 1, lcb = (tid & 1)*32;
    const __hip_bfloat16* ap = A  + (m0 + lr)*sA + lcb;
    const __hip_bfloat16* wp = Wt + (size_t)(n0 + lr)*sW + lcb;
    uint4 pa0 = *(const uint4*)(ap),      pa1 = *(const uint4*)(ap + 8);
    uint4 pa2 = *(const uint4*)(ap + 16), pa3 = *(const uint4*)(ap + 24);
    uint4 pw0 = *(const uint4*)(wp),      pw1 = *(const uint4*)(wp + 8);
    uint4 pw2 = *(const uint4*)(wp + 16), pw3 = *(const uint4*)(wp + 24);
    for (int kt = 0; kt < nk; ++kt) {
        __syncthreads();
        *(uint4*)&As[lr*72 + lcb]      = pa0;
        *(uint4*)&As[lr*72 + lcb + 8]  = pa1;
        *(uint4*)&As[lr*72 + lcb + 16] = pa2;
        *(uint4*)&As[lr*72 + lcb + 24] = pa3;
        *(uint4*)&Ws[lr*72 + lcb]      = pw0;
        *(uint4*)&Ws[lr*72 + lcb + 8]  = pw1;
        *(uint4*)&Ws[lr*72 + lcb + 16] = pw2;
        *(uint4*)&Ws[lr*72 + lcb + 24] = pw3;
        __syncthreads();
        if (kt + 1 < nk) {
            int ko = (kt + 1)*64;
            pa0 = *(const uint4*)(ap + ko);      pa1 = *(const uint4*)(ap + ko + 8);
            pa2 = *(const uint4*)(ap + ko + 16); pa3 = *(const uint4*)(ap + ko + 24);
            pw0 = *(const uint4*)(wp + ko);      pw1 = *(const uint4*)(wp + ko + 8);
            pw2 = *(const uint4*)(wp + ko + 16); pw3 = *(const uint4*)(wp + ko + 24);
        }
#pragma unroll
        for (int ks = 0; ks < 4; ++ks) {
            bf16x8 a0 = *(const bf16x8*)&As[(wm + l31)*72      + ks*16 + uh*8];
            bf16x8 a1 = *(const bf16x8*)&As[(wm + 32 + l31)*72 + ks*16 + uh*8];
            bf16x8 b0 = *(const bf16x8*)&Ws[(wn + l31)*72      + ks*16 + uh*8];
            bf16x8 b1 = *(const bf16x8*)&Ws[(wn + 32 + l31)*72 + ks*16 + uh*8];
            acc[0][0] = __builtin_amdgcn_mfma_f32_32x32x16_bf16(a0, b0, acc[0][0], 0, 0, 0);
            acc[0][1] = __builtin_amdgcn_mfma_f32_32x32x16_bf16(a0, b1, acc[0][1], 0, 0, 0);
            acc[1][0] = __builtin_amdgcn_mfma_f32_32x32x16_bf16(a1, b0, acc[1][0], 0, 0, 0);
            acc[1][1] = __builtin_amdgcn_mfma_f32_32x32x16_bf16(a1, b1, acc[1][1], 0, 0, 0);
        }
    }

#pragma unroll
    for (int nt = 0; nt < 2; ++nt) {
        int colg = n0 + wn + nt*32 + l31;
        int seg = fused ? (colg >> 8) : 0;
        int c8  = fused ? (colg & 255) : colg;
        float sc = (seg == 0) ? scale : 1.0f;
        float bz = bias ? bias[c8] : 0.f;
        __hip_bfloat16* cb = Cb ? (Cb + (size_t)seg*SZ) : (Cb);
#pragma unroll
        for (int mt = 0; mt < 2; ++mt) {
#pragma unroll
            for (int r = 0; r < 16; ++r) {
                size_t mg = m0 + wm + mt*32 + (r & 3) + ((r >> 2) << 3) + 4*uh;
                float v = (acc[mt][nt][r] + bz) * sc;
                if (pe)    v += pe[(mg & 31)*DM + c8];
                if (relu)  v = fmaxf(v, 0.f);
                if (resid) v += resid[mg*DM + c8];
                size_t oidx;
                if (fmt == 1)
                    oidx = (size_t)((mg & 31)*4 + (c8 >> 6))*65536 + (mg >> 5)*64 + (c8 & 63);
                else if (fmt == 2)
                    oidx = ((size_t)(c8 >> 6)*NS + (mg >> 5))*2048 + (mg & 31)*64 + (c8 & 63);
                else
                    oidx = mg*DM + c8;
                if (Cf) Cf[oidx] = v;
                if (cb) cb[oidx] = __float2bfloat16(v);
            }
        }
    }
}

// ================= T-attention: MFMA, one wave per head, tfmt QKV ============
union __align__(16) WLds { __hip_bfloat16 vt[64*40]; float ob[32*68]; };

__global__ __launch_bounds__(256) void attnT_k(const __hip_bfloat16* __restrict__ Q,
        const __hip_bfloat16* __restrict__ K, const __hip_bfloat16* __restrict__ V,
        float* __restrict__ O) {
    __shared__ WLds sm4[4];
    const int n = blockIdx.x;
    const int w = threadIdx.x >> 6, lane = threadIdx.x & 63;
    const int uh = lane >> 5, l31 = lane & 31;
    const size_t base = ((size_t)w*NS + n)*2048;   // head w, stock n

    bf16x8 kf[4], qf[4];
#pragma unroll
    for (int s = 0; s < 4; ++s) {
        kf[s] = *(const bf16x8*)(K + base + l31*64 + s*16 + uh*8);
        qf[s] = *(const bf16x8*)(Q + base + l31*64 + s*16 + uh*8);
    }
    __hip_bfloat16* vt = sm4[w].vt;
#pragma unroll
    for (int i = 0; i < 2; ++i) {
        int c = lane*2 + i;
        int dg = c >> 3, tg = c & 7;
        const ushort* vp = (const ushort*)(V + base + (tg*4)*64 + dg*4);
        ushort4 s0 = *(const ushort4*)(vp);
        ushort4 s1 = *(const ushort4*)(vp + 64);
        ushort4 s2 = *(const ushort4*)(vp + 128);
        ushort4 s3 = *(const ushort4*)(vp + 192);
        *(uint2*)&vt[(dg*4+0)*40 + tg*4] = make_uint2((unsigned)s0.x | ((unsigned)s1.x<<16),
                                                      (unsigned)s2.x | ((unsigned)s3.x<<16));
        *(uint2*)&vt[(dg*4+1)*40 + tg*4] = make_uint2((unsigned)s0.y | ((unsigned)s1.y<<16),
                                                      (unsigned)s2.y | ((unsigned)s3.y<<16));
        *(uint2*)&vt[(dg*4+2)*40 + tg*4] = make_uint2((unsigned)s0.z | ((unsigned)s1.z<<16),
                                                      (unsigned)s2.z | ((unsigned)s3.z<<16));
        *(uint2*)&vt[(dg*4+3)*40 + tg*4] = make_uint2((unsigned)s0.w | ((unsigned)s1.w<<16),
                                                      (unsigned)s2.w | ((unsigned)s3.w<<16));
    }

    f32x16 sa;
#pragma unroll
    for (int r = 0; r < 16; ++r) sa[r] = 0.f;
    sa = __builtin_amdgcn_mfma_f32_32x32x16_bf16(kf[0], qf[0], sa, 0, 0, 0);
    sa = __builtin_amdgcn_mfma_f32_32x32x16_bf16(kf[1], qf[1], sa, 0, 0, 0);
    sa = __builtin_amdgcn_mfma_f32_32x32x16_bf16(kf[2], qf[2], sa, 0, 0, 0);
    sa = __builtin_amdgcn_mfma_f32_32x32x16_bf16(kf[3], qf[3], sa, 0, 0, 0);

    float p[16], l = 0.f;
#pragma unroll
    for (int r = 0; r < 16; ++r) { p[r] = exp2f(sa[r]); l += p[r]; }
    l += __shfl_xor(l, 32);

    bf16x8 pf[2];
#pragma unroll
    for (int s = 0; s < 2; ++s) {
        unsigned A0 = pkbf(p[8*s+0], p[8*s+1]);
        unsigned A1 = pkbf(p[8*s+2], p[8*s+3]);
        unsigned B0 = pkbf(p[8*s+4], p[8*s+5]);
        unsigned B1 = pkbf(p[8*s+6], p[8*s+7]);
        unsigned xA0 = (unsigned)__shfl_xor((int)A0, 32);
        unsigned xA1 = (unsigned)__shfl_xor((int)A1, 32);
        unsigned xB0 = (unsigned)__shfl_xor((int)B0, 32);
        unsigned xB1 = (unsigned)__shfl_xor((int)B1, 32);
        union { uint4 i; bf16x8 v; } cv;
        cv.i = make_uint4(uh ? xB0 : A0, uh ? xB1 : A1,
                          uh ? B0 : xA0, uh ? B1 : xA1);
        pf[s] = cv.v;
    }

    f32x16 oa[2];
#pragma unroll
    for (int c = 0; c < 2; ++c) {
#pragma unroll
        for (int r = 0; r < 16; ++r) oa[c][r] = 0.f;
        bf16x8 v0 = *(const bf16x8*)&vt[(c*32 + l31)*40 + uh*8];
        bf16x8 v1 = *(const bf16x8*)&vt[(c*32 + l31)*40 + 16 + uh*8];
        oa[c] = __builtin_amdgcn_mfma_f32_32x32x16_bf16(v0, pf[0], oa[c], 0, 0, 0);
        oa[c] = __builtin_amdgcn_mfma_f32_32x32x16_bf16(v1, pf[1], oa[c], 0, 0, 0);
    }

    float invl = 1.0f / l;
    float* ob = sm4[w].ob;
#pragma unroll
    for (int c = 0; c < 2; ++c)
#pragma unroll
        for (int r = 0; r < 16; ++r) {
            int d = (r & 3) + ((r >> 2) << 3) + 4*uh + 32*c;
            ob[l31*68 + d] = oa[c][r] * invl;
        }
    int t = lane >> 1, d0 = (lane & 1)*32;
    float* gp = O + ((size_t)n*ST + t)*DM + w*64 + d0;
#pragma unroll
    for (int i = 0; i < 8; ++i) {
        float4 prev = *(const float4*)(gp + 4*i);
        float4 nv = *(const float4*)&ob[t*68 + d0 + 4*i];
        *(float4*)(gp + 4*i) = make_float4(prev.x+nv.x, prev.y+nv.y, prev.z+nv.z, prev.w+nv.w);
    }
}

// ================= S-attention: MFMA flash, sfmt QKV, XCD-swizzled ===========
// grid (tt, h, qt): blocks sharing a (tt,h) K/V slice differ by 128 in linear
// id (multiple of 8) -> same XCD L2 -> slice HBM-fetched ~once.
// Single 128-q strip per block (1024 blocks): VGPR ~64, 3-4 blocks/CU resident.
union __align__(16) LdsS {
    struct { __hip_bfloat16 K[64*72]; __hip_bfloat16 Vt[64*72]; } s;
    float Ob[4][32*68];
};

__global__ __launch_bounds__(256) void attnS_k(const __hip_bfloat16* __restrict__ Qb,
        const __hip_bfloat16* __restrict__ Kb, const __hip_bfloat16* __restrict__ Vb,
        float* __restrict__ O) {
    __shared__ LdsS sm;
    const int tt = blockIdx.x, h = blockIdx.y, qt = blockIdx.z;
    const int tid = threadIdx.x;
    const int w = tid >> 6, lane = tid & 63;
    const int uh = lane >> 5, l31 = lane & 31;
    const size_t hb = (size_t)(tt*4 + h)*65536;   // sfmt slice base

    // Q^T B-fragments straight from global (contiguous 64-elem rows)
    bf16x8 qf[4];
    {
        const __hip_bfloat16* qp = Qb + hb + (size_t)(qt*128 + w*32 + l31)*64 + 8*uh;
        qf[0] = *(const bf16x8*)(qp);
        qf[1] = *(const bf16x8*)(qp + 16);
        qf[2] = *(const bf16x8*)(qp + 32);
        qf[3] = *(const bf16x8*)(qp + 48);
    }

    f32x16 oa[2];
#pragma unroll
    for (int c = 0; c < 2; ++c)
#pragma unroll
        for (int r = 0; r < 16; ++r) oa[c][r] = 0.f;
    float lrun = 0.f;

    for (int kt = 0; kt < 16; ++kt) {
        __syncthreads();
        // stage K row-major (8 KB contiguous tile)
        {
            const __hip_bfloat16* kb = Kb + hb + (size_t)kt*4096;
#pragma unroll
            for (int i = 0; i < 2; ++i) {
                int c = tid*2 + i;
                int j = c >> 3, col = (c & 7)*8;
                *(uint4*)&sm.s.K[j*72 + col] = *(const uint4*)(kb + c*8);
            }
        }
        // stage V transposed
        {
            int j0 = (tid & 15)*4, cb = (tid >> 4)*4;
            const ushort* vp = (const ushort*)(Vb + hb + (size_t)(kt*64 + j0)*64 + cb);
            ushort4 s0 = *(const ushort4*)(vp);
            ushort4 s1 = *(const ushort4*)(vp + 64);
            ushort4 s2 = *(const ushort4*)(vp + 128);
            ushort4 s3 = *(const ushort4*)(vp + 192);
            *(uint2*)&sm.s.Vt[(cb+0)*72 + j0] = make_uint2((unsigned)s0.x | ((unsigned)s1.x<<16),
                                                           (unsigned)s2.x | ((unsigned)s3.x<<16));
            *(uint2*)&sm.s.Vt[(cb+1)*72 + j0] = make_uint2((unsigned)s0.y | ((unsigned)s1.y<<16),
                                                           (unsigned)s2.y | ((unsigned)s3.y<<16));
            *(uint2*)&sm.s.Vt[(cb+2)*72 + j0] = make_uint2((unsigned)s0.z | ((unsigned)s1.z<<16),
                                                           (unsigned)s2.z | ((unsigned)s3.z<<16));
            *(uint2*)&sm.s.Vt[(cb+3)*72 + j0] = make_uint2((unsigned)s0.w | ((unsigned)s1.w<<16),
                                                           (unsigned)s2.w | ((unsigned)s3.w<<16));
        }
        __syncthreads();

        // S^T = K * Q^T : 2 x (32x32), chained over hd=64 (Q pre-scaled)
        f32x16 sa[2];
#pragma unroll
        for (int ct = 0; ct < 2; ++ct) {
            f32x16 a2;
#pragma unroll
            for (int r = 0; r < 16; ++r) a2[r] = 0.f;
            const __hip_bfloat16* kb = &sm.s.K[(ct*32 + l31)*72 + 8*uh];
            a2 = __builtin_amdgcn_mfma_f32_32x32x16_bf16(*(const bf16x8*)(kb +  0), qf[0], a2, 0, 0, 0);
            a2 = __builtin_amdgcn_mfma_f32_32x32x16_bf16(*(const bf16x8*)(kb + 16), qf[1], a2, 0, 0, 0);
            a2 = __builtin_amdgcn_mfma_f32_32x32x16_bf16(*(const bf16x8*)(kb + 32), qf[2], a2, 0, 0, 0);
            a2 = __builtin_amdgcn_mfma_f32_32x32x16_bf16(*(const bf16x8*)(kb + 48), qf[3], a2, 0, 0, 0);
            sa[ct] = a2;
        }

        // no-max softmax accumulation: p = exp2(score'), l += sum
        float p[32];
        float rs = 0.f;
#pragma unroll
        for (int ct = 0; ct < 2; ++ct)
#pragma unroll
            for (int r = 0; r < 16; ++r) {
                float e = exp2f(sa[ct][r]);
                p[ct*16 + r] = e;
                rs += e;
            }
        rs += __shfl_xor(rs, 32);
        lrun += rs;

        // P^T B-fragments from registers + xor-32 shuffles
        bf16x8 bfr[4];
#pragma unroll
        for (int q = 0; q < 4; ++q) {
            int ct = q >> 1, b = (q & 1) << 3;
            unsigned A0 = pkbf(p[ct*16+b+0], p[ct*16+b+1]);
            unsigned A1 = pkbf(p[ct*16+b+2], p[ct*16+b+3]);
            unsigned B0 = pkbf(p[ct*16+b+4], p[ct*16+b+5]);
            unsigned B1 = pkbf(p[ct*16+b+6], p[ct*16+b+7]);
            unsigned xA0 = (unsigned)__shfl_xor((int)A0, 32);
            unsigned xA1 = (unsigned)__shfl_xor((int)A1, 32);
            unsigned xB0 = (unsigned)__shfl_xor((int)B0, 32);
            unsigned xB1 = (unsigned)__shfl_xor((int)B1, 32);
            union { uint4 i; bf16x8 v; } cv;
            cv.i = make_uint4(uh ? xB0 : A0, uh ? xB1 : A1,
                              uh ? B0 : xA0, uh ? B1 : xA1);
            bfr[q] = cv.v;
        }

        // O^T += V^T * P^T
#pragma unroll
        for (int c = 0; c < 2; ++c) {
            const __hip_bfloat16* vb = &sm.s.Vt[(c*32 + l31)*72 + 8*uh];
            oa[c] = __builtin_amdgcn_mfma_f32_32x32x16_bf16(*(const bf16x8*)(vb +  0), bfr[0], oa[c], 0, 0, 0);
            oa[c] = __builtin_amdgcn_mfma_f32_32x32x16_bf16(*(const bf16x8*)(vb + 16), bfr[1], oa[c], 0, 0, 0);
            oa[c] = __builtin_amdgcn_mfma_f32_32x32x16_bf16(*(const bf16x8*)(vb + 32), bfr[2], oa[c], 0, 0, 0);
            oa[c] = __builtin_amdgcn_mfma_f32_32x32x16_bf16(*(const bf16x8*)(vb + 48), bfr[3], oa[c], 0, 0, 0);
        }
    }

    // epilogue: transpose O^T via wave-local LDS, fused resid RMW, std layout
    __syncthreads();
    float invl = 1.0f / lrun;
    float* ob = sm.Ob[w];
#pragma unroll
    for (int c = 0; c < 2; ++c)
#pragma unroll
        for (int r = 0; r < 16; ++r) {
            int d = (r & 3) + ((r >> 2) << 3) + 4*uh + 32*c;
            ob[l31*68 + d] = oa[c][r] * invl;
        }
#pragma unroll
    for (int pp = 0; pp < 2; ++pp) {
        int qr = pp*16 + (lane >> 2);
        int dc = (lane & 3) << 4;
        float* gp = O + ((size_t)(qt*128 + w*32 + qr)*ST + tt)*DM + h*64 + dc;
#pragma unroll
        for (int i = 0; i < 4; ++i) {
            float4 prev = *(const float4*)(gp + 4*i);
            float4 nv = *(const float4*)&ob[qr*68 + dc + 4*i];
            *(float4*)(gp + 4*i) = make_float4(prev.x+nv.x, prev.y+nv.y,
                                               prev.z+nv.z, prev.w+nv.w);
        }
    }
}

// ================= temporal pooling + decoder ================================
__global__ __launch_bounds__(256) void final_k(const float* __restrict__ H,
        const float* __restrict__ HH, const float* __restrict__ dw,
        const float* __restrict__ db, float* __restrict__ out) {
    int n = blockIdx.x, d = threadIdx.x;
    int w = d >> 6, lane = d & 63;
    __shared__ float lam[ST];
    __shared__ float red[8];
    const float* hh = HH + (size_t)n*ST*DM;
    float4 qd = *(const float4*)(hh + 31*DM + lane*4);
#pragma unroll
    for (int i = 0; i < 8; ++i) {
        int t = w*8 + i;
        float4 h4 = *(const float4*)(hh + t*DM + lane*4);
        float s = wave_sum(h4.x*qd.x + h4.y*qd.y + h4.z*qd.z + h4.w*qd.w);
        if (lane == 0) lam[t] = s;
    }
    __syncthreads();
    float mx = -1e30f;
#pragma unroll
    for (int t = 0; t < ST; ++t) mx = fmaxf(mx, lam[t]);
    float sum = 0.f;
#pragma unroll
    for (int t = 0; t < ST; ++t) sum += __expf(lam[t]-mx);
    float acc = 0.f;
    const float* hrow = H + (size_t)n*ST*DM;
#pragma unroll
    for (int t = 0; t < ST; ++t) acc += __expf(lam[t]-mx) * hrow[t*DM + d];
    acc /= sum;
    float p0 = wave_sum(acc * dw[2*d+0]);
    float p1 = wave_sum(acc * dw[2*d+1]);
    if (lane == 0) { red[w] = p0; red[4 + w] = p1; }
    __syncthreads();
    if (d == 0) {
        float r0 = red[0]+red[1]+red[2]+red[3] + db[0];
        float r1 = red[4]+red[5]+red[6]+red[7] + db[1];
        out[(size_t)n*2+0] = r0;           out[(size_t)n*2+1] = r1;
        out[2048 + (size_t)n*2+0] = r0;    out[2048 + (size_t)n*2+1] = r1;
        out[4096 + (size_t)n*2+0] = r0;    out[4096 + (size_t)n*2+1] = r1;
        if (n == 0) out[6144] = 0.f;
    }
}

extern "C" void kernel_launch(void* const* d_in, const int* in_sizes, int n_in,
                              void* d_out, int out_size, void* d_ws, size_t ws_size,
                              hipStream_t stream) {
    const float* x     = (const float*)d_in[0];
    const float* emb_w = (const float*)d_in[5];
    const float* emb_b = (const float*)d_in[6];
    const float* pe    = (const float*)d_in[7];
    const float* t_g1  = (const float*)d_in[11];
    const float* t_b1  = (const float*)d_in[12];
    const float* t_g2  = (const float*)d_in[13];
    const float* t_b2  = (const float*)d_in[14];
    const float* t_bb1 = (const float*)d_in[16];
    const float* t_bb2 = (const float*)d_in[18];
    const float* s_g1  = (const float*)d_in[22];
    const float* s_b1  = (const float*)d_in[23];
    const float* s_g2  = (const float*)d_in[24];
    const float* s_b2  = (const float*)d_in[25];
    const float* s_bb1 = (const float*)d_in[27];
    const float* s_bb2 = (const float*)d_in[29];
    const float* dec_w = (const float*)d_in[31];
    const float* dec_b = (const float*)d_in[32];
    float* out = (float*)d_out;

    // ---- workspace layout (~143 MB) ----
    float* F0 = (float*)d_ws;                       // 32 MB
    float* F1 = F0 + SZ;                            // 32 MB
    __hip_bfloat16* H0 = (__hip_bfloat16*)(F1 + SZ);// 16 MB each
    __hip_bfloat16* H1 = H0 + SZ;                   // H1,H2,H3 contiguous (fused QKV)
    __hip_bfloat16* H2 = H1 + SZ;
    __hip_bfloat16* H3 = H2 + SZ;
    __hip_bfloat16* WT  = H3 + SZ;                  // 11 x 256x256
    __hip_bfloat16* WTE = WT + (size_t)11*DM*DM;    // 256x192
    __hip_bfloat16* XB  = WTE + (size_t)DM*KE;      // 32768x192

    // ---- conversions ----
    cvtx_k<<<ROWS*KE/256, 256, 0, stream>>>(x, XB);
    WPack wp;
    const int widx[11] = {8, 9, 10, 15, 17, 19, 20, 21, 26, 28, 30};
    for (int i = 0; i < 11; ++i) {
        wp.s[i] = (const float*)d_in[widx[i]];
        wp.d[i] = WT + (size_t)i*DM*DM;
    }
    cvtw_k<<<dim3(4, 4, 11), 256, 0, stream>>>(wp);
    cvte_k<<<DM, 192, 0, stream>>>(emb_w, WTE);

    dim3 gg(ROWS/128, 2);
    dim3 gq(ROWS/128, 6);                            // fused QKV: N = 768
    __hip_bfloat16* WqT = WT;                        // Wq|Wk|Wv contiguous
    __hip_bfloat16* W1  = WT + (size_t)3*DM*DM;
    __hip_bfloat16* W2  = WT + (size_t)4*DM*DM;
    __hip_bfloat16* SWq = WT + (size_t)5*DM*DM;      // SWq|SWk|SWv contiguous
    __hip_bfloat16* SW1 = WT + (size_t)8*DM*DM;
    __hip_bfloat16* SW2 = WT + (size_t)9*DM*DM;
    __hip_bfloat16* WTA = WT + (size_t)10*DM*DM;

    // ---- embed + PE (MFMA gemm, K=192 padded) ----
    mgemm_k<<<gg, 256, 0, stream>>>(XB, KE, 3, WTE, KE, emb_b, pe, nullptr, F0, nullptr, 0, 0, 1.f, 0);
    // ---- TAttention block ----
    ln_k<<<ROWS/4, 256, 0, stream>>>(F0, t_g1, t_b1, F1, H0);            // F1=xn, H0=xn(bf)
    mgemm_k<<<gq, 256, 0, stream>>>(H0, 256, 4, WqT, 256, nullptr, nullptr, nullptr, nullptr, H1, 0, 2, LOG2E, 1);
    attnT_k<<<NS, 256, 0, stream>>>(H1, H2, H3, F1);                     // F1 = xn+att
    ln_k<<<ROWS/4, 256, 0, stream>>>(F1, t_g2, t_b2, F0, H0);            // F0=xt, H0=xt(bf)
    mgemm_k<<<gg, 256, 0, stream>>>(H0, 256, 4, W1, 256, t_bb1, nullptr, nullptr, nullptr, H1, 1, 0, 1.f, 0);
    mgemm_k<<<gg, 256, 0, stream>>>(H1, 256, 4, W2, 256, t_bb2, nullptr, F0, F1, nullptr, 0, 0, 1.f, 0);   // F1 = h1
    // ---- SAttention block ----
    ln_k<<<ROWS/4, 256, 0, stream>>>(F1, s_g1, s_b1, F0, H0);            // F0=xn2, H0=xn2(bf)
    mgemm_k<<<gq, 256, 0, stream>>>(H0, 256, 4, SWq, 256, nullptr, nullptr, nullptr, nullptr, H1, 0, 1, 0.125f*LOG2E, 1);
    attnS_k<<<dim3(32, 4, 8), 256, 0, stream>>>(H1, H2, H3, F0);         // F0 = xn2+att
    ln_k<<<ROWS/4, 256, 0, stream>>>(F0, s_g2, s_b2, F1, H0);            // F1=xt2, H0=xt2(bf)
    mgemm_k<<<gg, 256, 0, stream>>>(H0, 256, 4, SW1, 256, s_bb1, nullptr, nullptr, nullptr, H1, 1, 0, 1.f, 0);
    mgemm_k<<<gg, 256, 0, stream>>>(H1, 256, 4, SW2, 256, s_bb2, nullptr, F1, F0, H2, 0, 0, 1.f, 0);       // F0=h2, H2=h2(bf)
    // ---- temporal attention + decoder ----
    mgemm_k<<<gg, 256, 0, stream>>>(H2, 256, 4, WTA, 256, nullptr, nullptr, nullptr, F1, nullptr, 0, 0, 1.f, 0);  // F1 = hh
    final_k<<<NS, 256, 0, stream>>>(F0, F1, dec_w, dec_b, out);
}

// Round 9
// 519.544 us; speedup vs baseline: 1.4587x; 1.4191x over previous
//
#include <hip/hip_runtime.h>
#include <hip/hip_bf16.h>
#include <math.h>

#define NS 1024
#define ST 32
#define DF 158
#define DM 256
#define KE 192                 // embed K padded to BK=64 multiple
#define ROWS (NS*ST)           // 32768
#define SZ ((size_t)ROWS*DM)   // 8388608 elems
#define LN_EPS 1e-5f
#define LOG2E 1.44269504088896f

typedef __attribute__((ext_vector_type(8)))  __bf16 bf16x8;
typedef __attribute__((ext_vector_type(16))) float  f32x16;

__device__ __forceinline__ float wave_sum(float v) {
#pragma unroll
    for (int o = 32; o > 0; o >>= 1) v += __shfl_xor(v, o);
    return v;
}

__device__ __forceinline__ unsigned pkbf(float a, float b) {
    __hip_bfloat16 ha = __float2bfloat16(a), hb = __float2bfloat16(b);
    unsigned short ua, ub;
    __builtin_memcpy(&ua, &ha, 2); __builtin_memcpy(&ub, &hb, 2);
    return (unsigned)ua | ((unsigned)ub << 16);
}

__device__ __forceinline__ float2 bf2x(unsigned u) {
    union { unsigned i; float f; } a, b;
    a.i = u << 16; b.i = u & 0xffff0000u;
    return make_float2(a.f, b.f);   // x = low element, y = high element
}

// add 8 floats (s[0..7]) onto a uint4 of 8 packed bf16, repack
__device__ __forceinline__ uint4 addpk(uint4 rv, const float* s) {
    float2 f0 = bf2x(rv.x), f1 = bf2x(rv.y), f2 = bf2x(rv.z), f3 = bf2x(rv.w);
    return make_uint4(pkbf(f0.x + s[0], f0.y + s[1]),
                      pkbf(f1.x + s[2], f1.y + s[3]),
                      pkbf(f2.x + s[4], f2.y + s[5]),
                      pkbf(f3.x + s[6], f3.y + s[7]));
}

// ================= conversion kernels (run every launch; idempotent) =========
__global__ __launch_bounds__(256) void cvtx_k(const float* __restrict__ x,
        __hip_bfloat16* __restrict__ xb) {
    int idx = blockIdx.x*256 + threadIdx.x;          // < 32768*192
    int r = idx / KE, c = idx - r*KE;
    float v = (c < DF) ? x[(size_t)r*DF + c] : 0.f;
    xb[idx] = __float2bfloat16(v);
}

struct WPack { const float* s[11]; __hip_bfloat16* d[11]; };

__global__ __launch_bounds__(256) void cvtw_k(WPack wp) {
    const float* W = wp.s[blockIdx.z];
    __hip_bfloat16* Wt = wp.d[blockIdx.z];
    __shared__ float t[64][65];
    int bi = blockIdx.x*64, bj = blockIdx.y*64;
    int r = threadIdx.x >> 2, c0 = (threadIdx.x & 3) * 16;
#pragma unroll
    for (int i = 0; i < 16; i += 4) {
        float4 v = *(const float4*)(W + (size_t)(bi + r)*DM + bj + c0 + i);
        t[r][c0+i+0] = v.x; t[r][c0+i+1] = v.y;
        t[r][c0+i+2] = v.z; t[r][c0+i+3] = v.w;
    }
    __syncthreads();
    unsigned u[8];
#pragma unroll
    for (int i = 0; i < 8; ++i) u[i] = pkbf(t[c0+2*i][r], t[c0+2*i+1][r]);
    __hip_bfloat16* op = Wt + (size_t)(bj + r)*DM + bi + c0;
    *(uint4*)(op)     = make_uint4(u[0], u[1], u[2], u[3]);
    *(uint4*)(op + 8) = make_uint4(u[4], u[5], u[6], u[7]);
}

__global__ __launch_bounds__(192) void cvte_k(const float* __restrict__ W,
        __hip_bfloat16* __restrict__ Wt) {
    int n = blockIdx.x, t = threadIdx.x;   // t < 192
    float v = (t < DF) ? W[(size_t)t*DM + n] : 0.f;
    Wt[(size_t)n*KE + t] = __float2bfloat16(v);
}

// ================= LayerNorm: bf16 in -> bf16 out, one wave per row =========
__global__ __launch_bounds__(256) void ln_k(const __hip_bfloat16* __restrict__ a,
        const float* __restrict__ g, const float* __restrict__ be,
        __hip_bfloat16* __restrict__ outb) {
    int w = threadIdx.x >> 6, lane = threadIdx.x & 63;
    size_t r = (size_t)blockIdx.x*4 + w;
    uint2 raw = *(const uint2*)(a + r*DM + lane*4);
    float2 v01 = bf2x(raw.x), v23 = bf2x(raw.y);
    float mu = wave_sum(v01.x+v01.y+v23.x+v23.y) * (1.0f/DM);
    float c0 = v01.x-mu, c1 = v01.y-mu, c2 = v23.x-mu, c3 = v23.y-mu;
    float var = wave_sum(c0*c0 + c1*c1 + c2*c2 + c3*c3) * (1.0f/DM);
    float rs = rsqrtf(var + LN_EPS);
    float4 g4 = *(const float4*)(g + lane*4);
    float4 b4 = *(const float4*)(be + lane*4);
    float o0 = c0*rs*g4.x + b4.x, o1 = c1*rs*g4.y + b4.y;
    float o2 = c2*rs*g4.z + b4.z, o3 = c3*rs*g4.w + b4.w;
    *(uint2*)(outb + r*DM + lane*4) = make_uint2(pkbf(o0, o1), pkbf(o2, o3));
}

// ================= MFMA GEMM: 64x128 tile, BK=64 ============================
// fmt: 0 = std [row][col]; 1 = sfmt [(t*4+h)][stock][d]; 2 = tfmt [h][stock][t][d]
// fused: colg>>8 selects output segment (Cb + seg*SZ); scale applies to seg 0 only.
// resid is bf16 (std layout). Cf optional fp32 out, Cb optional bf16 out.
__global__ __launch_bounds__(256) void mgemm_k(const __hip_bfloat16* __restrict__ A,
        int sA, int nk, const __hip_bfloat16* __restrict__ Wt, int sW,
        const float* __restrict__ bias, const float* __restrict__ pe,
        const __hip_bfloat16* __restrict__ resid, float* __restrict__ Cf,
        __hip_bfloat16* __restrict__ Cb, int relu, int fmt, float scale, int fused) {
    __shared__ __hip_bfloat16 As[64*72];
    __shared__ __hip_bfloat16 Ws[128*72];
    const int tid = threadIdx.x;
    const int w = tid >> 6, lane = tid & 63;
    const int uh = lane >> 5, l31 = lane & 31;
    const int wm = (w >> 1)*32, wn = (w & 1)*64;
    const size_t m0 = (size_t)blockIdx.x*64;
    const int n0 = blockIdx.y*128;

    f32x16 acc[2];
#pragma unroll
    for (int nt = 0; nt < 2; ++nt)
#pragma unroll
        for (int r = 0; r < 16; ++r) acc[nt][r] = 0.f;

    // A staging: 64 rows x 64 k; thread -> row tid>>2, 16-col quarter (2 uint4)
    // W staging: 128 rows x 64 k; thread -> row tid>>1, 32-col half (4 uint4)
    const int ra = tid >> 2, ca = (tid & 3)*16;
    const int rw = tid >> 1, cw = (tid & 1)*32;
    const __hip_bfloat16* ap = A  + (m0 + ra)*sA + ca;
    const __hip_bfloat16* wp = Wt + (size_t)(n0 + rw)*sW + cw;
    uint4 pa0 = *(const uint4*)(ap), pa1 = *(const uint4*)(ap + 8);
    uint4 pw0 = *(const uint4*)(wp),      pw1 = *(const uint4*)(wp + 8);
    uint4 pw2 = *(const uint4*)(wp + 16), pw3 = *(const uint4*)(wp + 24);
    for (int kt = 0; kt < nk; ++kt) {
        __syncthreads();
        *(uint4*)&As[ra*72 + ca]     = pa0;
        *(uint4*)&As[ra*72 + ca + 8] = pa1;
        *(uint4*)&Ws[rw*72 + cw]      = pw0;
        *(uint4*)&Ws[rw*72 + cw + 8]  = pw1;
        *(uint4*)&Ws[rw*72 + cw + 16] = pw2;
        *(uint4*)&Ws[rw*72 + cw + 24] = pw3;
        __syncthreads();
        if (kt + 1 < nk) {
            int ko = (kt + 1)*64;
            pa0 = *(const uint4*)(ap + ko);      pa1 = *(const uint4*)(ap + ko + 8);
            pw0 = *(const uint4*)(wp + ko);      pw1 = *(const uint4*)(wp + ko + 8);
            pw2 = *(const uint4*)(wp + ko + 16); pw3 = *(const uint4*)(wp + ko + 24);
        }
#pragma unroll
        for (int ks = 0; ks < 4; ++ks) {
            bf16x8 a0 = *(const bf16x8*)&As[(wm + l31)*72      + ks*16 + uh*8];
            bf16x8 b0 = *(const bf16x8*)&Ws[(wn + l31)*72      + ks*16 + uh*8];
            bf16x8 b1 = *(const bf16x8*)&Ws[(wn + 32 + l31)*72 + ks*16 + uh*8];
            acc[0] = __builtin_amdgcn_mfma_f32_32x32x16_bf16(a0, b0, acc[0], 0, 0, 0);
            acc[1] = __builtin_amdgcn_mfma_f32_32x32x16_bf16(a0, b1, acc[1], 0, 0, 0);
        }
    }

#pragma unroll
    for (int nt = 0; nt < 2; ++nt) {
        int colg = n0 + wn + nt*32 + l31;
        int seg = fused ? (colg >> 8) : 0;
        int c8  = fused ? (colg & 255) : colg;
        float sc = (seg == 0) ? scale : 1.0f;
        float bz = bias ? bias[c8] : 0.f;
        __hip_bfloat16* cb = Cb ? (Cb + (size_t)seg*SZ) : Cb;
#pragma unroll
        for (int r = 0; r < 16; ++r) {
            size_t mg = m0 + wm + (r & 3) + ((r >> 2) << 3) + 4*uh;
            float v = (acc[nt][r] + bz) * sc;
            if (pe)    v += pe[(mg & 31)*DM + c8];
            if (relu)  v = fmaxf(v, 0.f);
            if (resid) v += __bfloat162float(resid[mg*DM + c8]);
            size_t oidx;
            if (fmt == 1)
                oidx = (size_t)((mg & 31)*4 + (c8 >> 6))*65536 + (mg >> 5)*64 + (c8 & 63);
            else if (fmt == 2)
                oidx = ((size_t)(c8 >> 6)*NS + (mg >> 5))*2048 + (mg & 31)*64 + (c8 & 63);
            else
                oidx = mg*DM + c8;
            if (Cf) Cf[oidx] = v;
            if (cb) cb[oidx] = __float2bfloat16(v);
        }
    }
}

// ================= T-attention: MFMA, one wave per head, tfmt QKV ============
// out = resid + att, bf16 -> bf16 (std layout)
union __align__(16) WLds { __hip_bfloat16 vt[64*40]; float ob[32*68]; };

__global__ __launch_bounds__(256) void attnT_k(const __hip_bfloat16* __restrict__ Q,
        const __hip_bfloat16* __restrict__ K, const __hip_bfloat16* __restrict__ V,
        const __hip_bfloat16* __restrict__ R, __hip_bfloat16* __restrict__ O) {
    __shared__ WLds sm4[4];
    const int n = blockIdx.x;
    const int w = threadIdx.x >> 6, lane = threadIdx.x & 63;
    const int uh = lane >> 5, l31 = lane & 31;
    const size_t base = ((size_t)w*NS + n)*2048;   // head w, stock n

    bf16x8 kf[4], qf[4];
#pragma unroll
    for (int s = 0; s < 4; ++s) {
        kf[s] = *(const bf16x8*)(K + base + l31*64 + s*16 + uh*8);
        qf[s] = *(const bf16x8*)(Q + base + l31*64 + s*16 + uh*8);
    }
    __hip_bfloat16* vt = sm4[w].vt;
#pragma unroll
    for (int i = 0; i < 2; ++i) {
        int c = lane*2 + i;
        int dg = c >> 3, tg = c & 7;
        const ushort* vp = (const ushort*)(V + base + (tg*4)*64 + dg*4);
        ushort4 s0 = *(const ushort4*)(vp);
        ushort4 s1 = *(const ushort4*)(vp + 64);
        ushort4 s2 = *(const ushort4*)(vp + 128);
        ushort4 s3 = *(const ushort4*)(vp + 192);
        *(uint2*)&vt[(dg*4+0)*40 + tg*4] = make_uint2((unsigned)s0.x | ((unsigned)s1.x<<16),
                                                      (unsigned)s2.x | ((unsigned)s3.x<<16));
        *(uint2*)&vt[(dg*4+1)*40 + tg*4] = make_uint2((unsigned)s0.y | ((unsigned)s1.y<<16),
                                                      (unsigned)s2.y | ((unsigned)s3.y<<16));
        *(uint2*)&vt[(dg*4+2)*40 + tg*4] = make_uint2((unsigned)s0.z | ((unsigned)s1.z<<16),
                                                      (unsigned)s2.z | ((unsigned)s3.z<<16));
        *(uint2*)&vt[(dg*4+3)*40 + tg*4] = make_uint2((unsigned)s0.w | ((unsigned)s1.w<<16),
                                                      (unsigned)s2.w | ((unsigned)s3.w<<16));
    }

    f32x16 sa;
#pragma unroll
    for (int r = 0; r < 16; ++r) sa[r] = 0.f;
    sa = __builtin_amdgcn_mfma_f32_32x32x16_bf16(kf[0], qf[0], sa, 0, 0, 0);
    sa = __builtin_amdgcn_mfma_f32_32x32x16_bf16(kf[1], qf[1], sa, 0, 0, 0);
    sa = __builtin_amdgcn_mfma_f32_32x32x16_bf16(kf[2], qf[2], sa, 0, 0, 0);
    sa = __builtin_amdgcn_mfma_f32_32x32x16_bf16(kf[3], qf[3], sa, 0, 0, 0);

    float p[16], l = 0.f;
#pragma unroll
    for (int r = 0; r < 16; ++r) { p[r] = exp2f(sa[r]); l += p[r]; }
    l += __shfl_xor(l, 32);

    bf16x8 pf[2];
#pragma unroll
    for (int s = 0; s < 2; ++s) {
        unsigned A0 = pkbf(p[8*s+0], p[8*s+1]);
        unsigned A1 = pkbf(p[8*s+2], p[8*s+3]);
        unsigned B0 = pkbf(p[8*s+4], p[8*s+5]);
        unsigned B1 = pkbf(p[8*s+6], p[8*s+7]);
        unsigned xA0 = (unsigned)__shfl_xor((int)A0, 32);
        unsigned xA1 = (unsigned)__shfl_xor((int)A1, 32);
        unsigned xB0 = (unsigned)__shfl_xor((int)B0, 32);
        unsigned xB1 = (unsigned)__shfl_xor((int)B1, 32);
        union { uint4 i; bf16x8 v; } cv;
        cv.i = make_uint4(uh ? xB0 : A0, uh ? xB1 : A1,
                          uh ? B0 : xA0, uh ? B1 : xA1);
        pf[s] = cv.v;
    }

    f32x16 oa[2];
#pragma unroll
    for (int c = 0; c < 2; ++c) {
#pragma unroll
        for (int r = 0; r < 16; ++r) oa[c][r] = 0.f;
        bf16x8 v0 = *(const bf16x8*)&vt[(c*32 + l31)*40 + uh*8];
        bf16x8 v1 = *(const bf16x8*)&vt[(c*32 + l31)*40 + 16 + uh*8];
        oa[c] = __builtin_amdgcn_mfma_f32_32x32x16_bf16(v0, pf[0], oa[c], 0, 0, 0);
        oa[c] = __builtin_amdgcn_mfma_f32_32x32x16_bf16(v1, pf[1], oa[c], 0, 0, 0);
    }

    float invl = 1.0f / l;
    float* ob = sm4[w].ob;
#pragma unroll
    for (int c = 0; c < 2; ++c)
#pragma unroll
        for (int r = 0; r < 16; ++r) {
            int d = (r & 3) + ((r >> 2) << 3) + 4*uh + 32*c;
            ob[l31*68 + d] = oa[c][r] * invl;
        }
    int t = lane >> 1, d0 = (lane & 1)*32;
    size_t gi = ((size_t)n*ST + t)*DM + w*64 + d0;
#pragma unroll
    for (int i = 0; i < 4; ++i) {
        uint4 rv = *(const uint4*)(R + gi + 8*i);
        *(uint4*)(O + gi + 8*i) = addpk(rv, &ob[t*68 + d0 + 8*i]);
    }
}

// ================= S-attention: MFMA flash, sfmt QKV, XCD-swizzled ===========
// grid (tt, h, qt): blocks sharing a (tt,h) K/V slice land on one XCD.
// out = resid + att, bf16 -> bf16 (std layout).
union __align__(16) LdsS {
    struct { __hip_bfloat16 K[64*72]; __hip_bfloat16 Vt[64*72]; } s;
    float Ob[4][32*68];
};

__global__ __launch_bounds__(256) void attnS_k(const __hip_bfloat16* __restrict__ Qb,
        const __hip_bfloat16* __restrict__ Kb, const __hip_bfloat16* __restrict__ Vb,
        const __hip_bfloat16* __restrict__ R, __hip_bfloat16* __restrict__ O) {
    __shared__ LdsS sm;
    const int tt = blockIdx.x, h = blockIdx.y, qt = blockIdx.z;
    const int tid = threadIdx.x;
    const int w = tid >> 6, lane = tid & 63;
    const int uh = lane >> 5, l31 = lane & 31;
    const size_t hb = (size_t)(tt*4 + h)*65536;   // sfmt slice base

    bf16x8 qf[4];
    {
        const __hip_bfloat16* qp = Qb + hb + (size_t)(qt*128 + w*32 + l31)*64 + 8*uh;
        qf[0] = *(const bf16x8*)(qp);
        qf[1] = *(const bf16x8*)(qp + 16);
        qf[2] = *(const bf16x8*)(qp + 32);
        qf[3] = *(const bf16x8*)(qp + 48);
    }

    f32x16 oa[2];
#pragma unroll
    for (int c = 0; c < 2; ++c)
#pragma unroll
        for (int r = 0; r < 16; ++r) oa[c][r] = 0.f;
    float lrun = 0.f;

    for (int kt = 0; kt < 16; ++kt) {
        __syncthreads();
        {
            const __hip_bfloat16* kb = Kb + hb + (size_t)kt*4096;
#pragma unroll
            for (int i = 0; i < 2; ++i) {
                int c = tid*2 + i;
                int j = c >> 3, col = (c & 7)*8;
                *(uint4*)&sm.s.K[j*72 + col] = *(const uint4*)(kb + c*8);
            }
        }
        {
            int j0 = (tid & 15)*4, cb = (tid >> 4)*4;
            const ushort* vp = (const ushort*)(Vb + hb + (size_t)(kt*64 + j0)*64 + cb);
            ushort4 s0 = *(const ushort4*)(vp);
            ushort4 s1 = *(const ushort4*)(vp + 64);
            ushort4 s2 = *(const ushort4*)(vp + 128);
            ushort4 s3 = *(const ushort4*)(vp + 192);
            *(uint2*)&sm.s.Vt[(cb+0)*72 + j0] = make_uint2((unsigned)s0.x | ((unsigned)s1.x<<16),
                                                           (unsigned)s2.x | ((unsigned)s3.x<<16));
            *(uint2*)&sm.s.Vt[(cb+1)*72 + j0] = make_uint2((unsigned)s0.y | ((unsigned)s1.y<<16),
                                                           (unsigned)s2.y | ((unsigned)s3.y<<16));
            *(uint2*)&sm.s.Vt[(cb+2)*72 + j0] = make_uint2((unsigned)s0.z | ((unsigned)s1.z<<16),
                                                           (unsigned)s2.z | ((unsigned)s3.z<<16));
            *(uint2*)&sm.s.Vt[(cb+3)*72 + j0] = make_uint2((unsigned)s0.w | ((unsigned)s1.w<<16),
                                                           (unsigned)s2.w | ((unsigned)s3.w<<16));
        }
        __syncthreads();

        f32x16 sa[2];
#pragma unroll
        for (int ct = 0; ct < 2; ++ct) {
            f32x16 a2;
#pragma unroll
            for (int r = 0; r < 16; ++r) a2[r] = 0.f;
            const __hip_bfloat16* kb = &sm.s.K[(ct*32 + l31)*72 + 8*uh];
            a2 = __builtin_amdgcn_mfma_f32_32x32x16_bf16(*(const bf16x8*)(kb +  0), qf[0], a2, 0, 0, 0);
            a2 = __builtin_amdgcn_mfma_f32_32x32x16_bf16(*(const bf16x8*)(kb + 16), qf[1], a2, 0, 0, 0);
            a2 = __builtin_amdgcn_mfma_f32_32x32x16_bf16(*(const bf16x8*)(kb + 32), qf[2], a2, 0, 0, 0);
            a2 = __builtin_amdgcn_mfma_f32_32x32x16_bf16(*(const bf16x8*)(kb + 48), qf[3], a2, 0, 0, 0);
            sa[ct] = a2;
        }

        float p[32];
        float rs = 0.f;
#pragma unroll
        for (int ct = 0; ct < 2; ++ct)
#pragma unroll
            for (int r = 0; r < 16; ++r) {
                float e = exp2f(sa[ct][r]);
                p[ct*16 + r] = e;
                rs += e;
            }
        rs += __shfl_xor(rs, 32);
        lrun += rs;

        bf16x8 bfr[4];
#pragma unroll
        for (int q = 0; q < 4; ++q) {
            int ct = q >> 1, b = (q & 1) << 3;
            unsigned A0 = pkbf(p[ct*16+b+0], p[ct*16+b+1]);
            unsigned A1 = pkbf(p[ct*16+b+2], p[ct*16+b+3]);
            unsigned B0 = pkbf(p[ct*16+b+4], p[ct*16+b+5]);
            unsigned B1 = pkbf(p[ct*16+b+6], p[ct*16+b+7]);
            unsigned xA0 = (unsigned)__shfl_xor((int)A0, 32);
            unsigned xA1 = (unsigned)__shfl_xor((int)A1, 32);
            unsigned xB0 = (unsigned)__shfl_xor((int)B0, 32);
            unsigned xB1 = (unsigned)__shfl_xor((int)B1, 32);
            union { uint4 i; bf16x8 v; } cv;
            cv.i = make_uint4(uh ? xB0 : A0, uh ? xB1 : A1,
                              uh ? B0 : xA0, uh ? B1 : xA1);
            bfr[q] = cv.v;
        }

#pragma unroll
        for (int c = 0; c < 2; ++c) {
            const __hip_bfloat16* vb = &sm.s.Vt[(c*32 + l31)*72 + 8*uh];
            oa[c] = __builtin_amdgcn_mfma_f32_32x32x16_bf16(*(const bf16x8*)(vb +  0), bfr[0], oa[c], 0, 0, 0);
            oa[c] = __builtin_amdgcn_mfma_f32_32x32x16_bf16(*(const bf16x8*)(vb + 16), bfr[1], oa[c], 0, 0, 0);
            oa[c] = __builtin_amdgcn_mfma_f32_32x32x16_bf16(*(const bf16x8*)(vb + 32), bfr[2], oa[c], 0, 0, 0);
            oa[c] = __builtin_amdgcn_mfma_f32_32x32x16_bf16(*(const bf16x8*)(vb + 48), bfr[3], oa[c], 0, 0, 0);
        }
    }

    __syncthreads();
    float invl = 1.0f / lrun;
    float* ob = sm.Ob[w];
#pragma unroll
    for (int c = 0; c < 2; ++c)
#pragma unroll
        for (int r = 0; r < 16; ++r) {
            int d = (r & 3) + ((r >> 2) << 3) + 4*uh + 32*c;
            ob[l31*68 + d] = oa[c][r] * invl;
        }
#pragma unroll
    for (int pp = 0; pp < 2; ++pp) {
        int qr = pp*16 + (lane >> 2);
        int dc = (lane & 3) << 4;
        size_t gi = ((size_t)(qt*128 + w*32 + qr)*ST + tt)*DM + h*64 + dc;
#pragma unroll
        for (int i = 0; i < 2; ++i) {
            uint4 rv = *(const uint4*)(R + gi + 8*i);
            *(uint4*)(O + gi + 8*i) = addpk(rv, &ob[qr*68 + dc + 8*i]);
        }
    }
}

// ================= temporal pooling + decoder ================================
__global__ __launch_bounds__(256) void final_k(const __hip_bfloat16* __restrict__ H,
        const float* __restrict__ HH, const float* __restrict__ dw,
        const float* __restrict__ db, float* __restrict__ out) {
    int n = blockIdx.x, d = threadIdx.x;
    int w = d >> 6, lane = d & 63;
    __shared__ float lam[ST];
    __shared__ float red[8];
    const float* hh = HH + (size_t)n*ST*DM;
    float4 qd = *(const float4*)(hh + 31*DM + lane*4);
#pragma unroll
    for (int i = 0; i < 8; ++i) {
        int t = w*8 + i;
        float4 h4 = *(const float4*)(hh + t*DM + lane*4);
        float s = wave_sum(h4.x*qd.x + h4.y*qd.y + h4.z*qd.z + h4.w*qd.w);
        if (lane == 0) lam[t] = s;
    }
    __syncthreads();
    float mx = -1e30f;
#pragma unroll
    for (int t = 0; t < ST; ++t) mx = fmaxf(mx, lam[t]);
    float sum = 0.f;
#pragma unroll
    for (int t = 0; t < ST; ++t) sum += __expf(lam[t]-mx);
    float acc = 0.f;
    const __hip_bfloat16* hrow = H + (size_t)n*ST*DM;
#pragma unroll
    for (int t = 0; t < ST; ++t)
        acc += __expf(lam[t]-mx) * __bfloat162float(hrow[t*DM + d]);
    acc /= sum;
    float p0 = wave_sum(acc * dw[2*d+0]);
    float p1 = wave_sum(acc * dw[2*d+1]);
    if (lane == 0) { red[w] = p0; red[4 + w] = p1; }
    __syncthreads();
    if (d == 0) {
        float r0 = red[0]+red[1]+red[2]+red[3] + db[0];
        float r1 = red[4]+red[5]+red[6]+red[7] + db[1];
        out[(size_t)n*2+0] = r0;           out[(size_t)n*2+1] = r1;
        out[2048 + (size_t)n*2+0] = r0;    out[2048 + (size_t)n*2+1] = r1;
        out[4096 + (size_t)n*2+0] = r0;    out[4096 + (size_t)n*2+1] = r1;
        if (n == 0) out[6144] = 0.f;
    }
}

extern "C" void kernel_launch(void* const* d_in, const int* in_sizes, int n_in,
                              void* d_out, int out_size, void* d_ws, size_t ws_size,
                              hipStream_t stream) {
    const float* x     = (const float*)d_in[0];
    const float* emb_w = (const float*)d_in[5];
    const float* emb_b = (const float*)d_in[6];
    const float* pe    = (const float*)d_in[7];
    const float* t_g1  = (const float*)d_in[11];
    const float* t_b1  = (const float*)d_in[12];
    const float* t_g2  = (const float*)d_in[13];
    const float* t_b2  = (const float*)d_in[14];
    const float* t_bb1 = (const float*)d_in[16];
    const float* t_bb2 = (const float*)d_in[18];
    const float* s_g1  = (const float*)d_in[22];
    const float* s_b1  = (const float*)d_in[23];
    const float* s_g2  = (const float*)d_in[24];
    const float* s_b2  = (const float*)d_in[25];
    const float* s_bb1 = (const float*)d_in[27];
    const float* s_bb2 = (const float*)d_in[29];
    const float* dec_w = (const float*)d_in[31];
    const float* dec_b = (const float*)d_in[32];
    float* out = (float*)d_out;

    // ---- workspace layout (~126 MB) ----
    float* F0 = (float*)d_ws;                       // 32 MB (hh, fp32)
    __hip_bfloat16* B0 = (__hip_bfloat16*)(F0 + SZ);// 16 MB each
    __hip_bfloat16* B1 = B0 + SZ;
    __hip_bfloat16* B2 = B1 + SZ;                   // B2,B3,B4 contiguous (fused QKV)
    __hip_bfloat16* B3 = B2 + SZ;
    __hip_bfloat16* B4 = B3 + SZ;
    __hip_bfloat16* WT  = B4 + SZ;                  // 11 x 256x256
    __hip_bfloat16* WTE = WT + (size_t)11*DM*DM;    // 256x192
    __hip_bfloat16* XB  = WTE + (size_t)DM*KE;      // 32768x192

    // ---- conversions ----
    cvtx_k<<<ROWS*KE/256, 256, 0, stream>>>(x, XB);
    WPack wp;
    const int widx[11] = {8, 9, 10, 15, 17, 19, 20, 21, 26, 28, 30};
    for (int i = 0; i < 11; ++i) {
        wp.s[i] = (const float*)d_in[widx[i]];
        wp.d[i] = WT + (size_t)i*DM*DM;
    }
    cvtw_k<<<dim3(4, 4, 11), 256, 0, stream>>>(wp);
    cvte_k<<<DM, 192, 0, stream>>>(emb_w, WTE);

    dim3 gg(ROWS/64, 2);                             // std gemm: 1024 blocks
    dim3 gq(ROWS/64, 6);                             // fused QKV: 3072 blocks
    __hip_bfloat16* WqT = WT;                        // Wq|Wk|Wv contiguous
    __hip_bfloat16* W1  = WT + (size_t)3*DM*DM;
    __hip_bfloat16* W2  = WT + (size_t)4*DM*DM;
    __hip_bfloat16* SWq = WT + (size_t)5*DM*DM;      // SWq|SWk|SWv contiguous
    __hip_bfloat16* SW1 = WT + (size_t)8*DM*DM;
    __hip_bfloat16* SW2 = WT + (size_t)9*DM*DM;
    __hip_bfloat16* WTA = WT + (size_t)10*DM*DM;

    // ---- embed + PE ----
    mgemm_k<<<gg, 256, 0, stream>>>(XB, KE, 3, WTE, KE, emb_b, pe, nullptr, nullptr, B0, 0, 0, 1.f, 0);
    // ---- TAttention block ----
    ln_k<<<ROWS/4, 256, 0, stream>>>(B0, t_g1, t_b1, B1);                 // B1 = xn
    mgemm_k<<<gq, 256, 0, stream>>>(B1, 256, 4, WqT, 256, nullptr, nullptr, nullptr, nullptr, B2, 0, 2, LOG2E, 1);
    attnT_k<<<NS, 256, 0, stream>>>(B2, B3, B4, B1, B0);                  // B0 = xn+att
    ln_k<<<ROWS/4, 256, 0, stream>>>(B0, t_g2, t_b2, B1);                 // B1 = xt
    mgemm_k<<<gg, 256, 0, stream>>>(B1, 256, 4, W1, 256, t_bb1, nullptr, nullptr, nullptr, B2, 1, 0, 1.f, 0);
    mgemm_k<<<gg, 256, 0, stream>>>(B2, 256, 4, W2, 256, t_bb2, nullptr, B1, nullptr, B0, 0, 0, 1.f, 0);  // B0 = h1
    // ---- SAttention block ----
    ln_k<<<ROWS/4, 256, 0, stream>>>(B0, s_g1, s_b1, B1);                 // B1 = xn2
    mgemm_k<<<gq, 256, 0, stream>>>(B1, 256, 4, SWq, 256, nullptr, nullptr, nullptr, nullptr, B2, 0, 1, 0.125f*LOG2E, 1);
    attnS_k<<<dim3(32, 4, 8), 256, 0, stream>>>(B2, B3, B4, B1, B0);      // B0 = xn2+att
    ln_k<<<ROWS/4, 256, 0, stream>>>(B0, s_g2, s_b2, B1);                 // B1 = xt2
    mgemm_k<<<gg, 256, 0, stream>>>(B1, 256, 4, SW1, 256, s_bb1, nullptr, nullptr, nullptr, B2, 1, 0, 1.f, 0);
    mgemm_k<<<gg, 256, 0, stream>>>(B2, 256, 4, SW2, 256, s_bb2, nullptr, B1, nullptr, B0, 0, 0, 1.f, 0); // B0 = h2
    // ---- temporal attention + decoder ----
    mgemm_k<<<gg, 256, 0, stream>>>(B0, 256, 4, WTA, 256, nullptr, nullptr, nullptr, F0, nullptr, 0, 0, 1.f, 0);  // F0 = hh (fp32)
    final_k<<<NS, 256, 0, stream>>>(B0, F0, dec_w, dec_b, out);
}

// Round 10
// 499.842 us; speedup vs baseline: 1.5162x; 1.0394x over previous
//
#include <hip/hip_runtime.h>
#include <hip/hip_bf16.h>
#include <math.h>

#define NS 1024
#define ST 32
#define DF 158
#define DM 256
#define KE 192                 // embed K padded to BK=64 multiple
#define ROWS (NS*ST)           // 32768
#define SZ ((size_t)ROWS*DM)   // 8388608 elems
#define LN_EPS 1e-5f
#define LOG2E 1.44269504088896f

typedef __attribute__((ext_vector_type(8)))  __bf16 bf16x8;
typedef __attribute__((ext_vector_type(16))) float  f32x16;

__device__ __forceinline__ float wave_sum(float v) {
#pragma unroll
    for (int o = 32; o > 0; o >>= 1) v += __shfl_xor(v, o);
    return v;
}

// accurate RNE pack (weight conversion only)
__device__ __forceinline__ unsigned pkbf(float a, float b) {
    __hip_bfloat16 ha = __float2bfloat16(a), hb = __float2bfloat16(b);
    unsigned short ua, ub;
    __builtin_memcpy(&ua, &ha, 2); __builtin_memcpy(&ub, &hb, 2);
    return (unsigned)ua | ((unsigned)ub << 16);
}

// fast pack: round-half-up (3-5 VALU ops). Differs from RNE only on exact ties.
__device__ __forceinline__ unsigned pkbf_fast(float a, float b) {
    unsigned ua = __float_as_uint(a) + 0x8000u;
    unsigned ub = __float_as_uint(b) + 0x8000u;
    return (ua >> 16) | (ub & 0xffff0000u);
}

__device__ __forceinline__ unsigned short sbf(float a) {
    return (unsigned short)((__float_as_uint(a) + 0x8000u) >> 16);
}

__device__ __forceinline__ float2 bf2x(unsigned u) {
    union { unsigned i; float f; } a, b;
    a.i = u << 16; b.i = u & 0xffff0000u;
    return make_float2(a.f, b.f);   // x = low element, y = high element
}

// add 8 floats (s[0..7]) onto a uint4 of 8 packed bf16, repack (fast)
__device__ __forceinline__ uint4 addpk(uint4 rv, const float* s) {
    float2 f0 = bf2x(rv.x), f1 = bf2x(rv.y), f2 = bf2x(rv.z), f3 = bf2x(rv.w);
    return make_uint4(pkbf_fast(f0.x + s[0], f0.y + s[1]),
                      pkbf_fast(f1.x + s[2], f1.y + s[3]),
                      pkbf_fast(f2.x + s[4], f2.y + s[5]),
                      pkbf_fast(f3.x + s[6], f3.y + s[7]));
}

// ================= conversion kernels (run every launch; idempotent) =========
__global__ __launch_bounds__(256) void cvtx_k(const float* __restrict__ x,
        __hip_bfloat16* __restrict__ xb) {
    int idx = blockIdx.x*256 + threadIdx.x;          // < 32768*192
    int r = idx / KE, c = idx - r*KE;
    float v = (c < DF) ? x[(size_t)r*DF + c] : 0.f;
    xb[idx] = __float2bfloat16(v);
}

struct WPack { const float* s[11]; __hip_bfloat16* d[11]; };

__global__ __launch_bounds__(256) void cvtw_k(WPack wp) {
    const float* W = wp.s[blockIdx.z];
    __hip_bfloat16* Wt = wp.d[blockIdx.z];
    __shared__ float t[64][65];
    int bi = blockIdx.x*64, bj = blockIdx.y*64;
    int r = threadIdx.x >> 2, c0 = (threadIdx.x & 3) * 16;
#pragma unroll
    for (int i = 0; i < 16; i += 4) {
        float4 v = *(const float4*)(W + (size_t)(bi + r)*DM + bj + c0 + i);
        t[r][c0+i+0] = v.x; t[r][c0+i+1] = v.y;
        t[r][c0+i+2] = v.z; t[r][c0+i+3] = v.w;
    }
    __syncthreads();
    unsigned u[8];
#pragma unroll
    for (int i = 0; i < 8; ++i) u[i] = pkbf(t[c0+2*i][r], t[c0+2*i+1][r]);
    __hip_bfloat16* op = Wt + (size_t)(bj + r)*DM + bi + c0;
    *(uint4*)(op)     = make_uint4(u[0], u[1], u[2], u[3]);
    *(uint4*)(op + 8) = make_uint4(u[4], u[5], u[6], u[7]);
}

__global__ __launch_bounds__(192) void cvte_k(const float* __restrict__ W,
        __hip_bfloat16* __restrict__ Wt) {
    int n = blockIdx.x, t = threadIdx.x;   // t < 192
    float v = (t < DF) ? W[(size_t)t*DM + n] : 0.f;
    Wt[(size_t)n*KE + t] = __float2bfloat16(v);
}

// ================= LayerNorm: bf16 in -> bf16 out, one wave per row =========
__global__ __launch_bounds__(256) void ln_k(const __hip_bfloat16* __restrict__ a,
        const float* __restrict__ g, const float* __restrict__ be,
        __hip_bfloat16* __restrict__ outb) {
    int w = threadIdx.x >> 6, lane = threadIdx.x & 63;
    size_t r = (size_t)blockIdx.x*4 + w;
    uint2 raw = *(const uint2*)(a + r*DM + lane*4);
    float2 v01 = bf2x(raw.x), v23 = bf2x(raw.y);
    float mu = wave_sum(v01.x+v01.y+v23.x+v23.y) * (1.0f/DM);
    float c0 = v01.x-mu, c1 = v01.y-mu, c2 = v23.x-mu, c3 = v23.y-mu;
    float var = wave_sum(c0*c0 + c1*c1 + c2*c2 + c3*c3) * (1.0f/DM);
    float rs = rsqrtf(var + LN_EPS);
    float4 g4 = *(const float4*)(g + lane*4);
    float4 b4 = *(const float4*)(be + lane*4);
    float o0 = c0*rs*g4.x + b4.x, o1 = c1*rs*g4.y + b4.y;
    float o2 = c2*rs*g4.z + b4.z, o3 = c3*rs*g4.w + b4.w;
    *(uint2*)(outb + r*DM + lane*4) = make_uint2(pkbf_fast(o0, o1), pkbf_fast(o2, o3));
}

// ================= MFMA GEMM: 64x128 tile, BK=64 ============================
// fmt: 0 = std [row][col]; 1 = sfmt [(t*4+h)][stock][d]; 2 = tfmt [h][stock][t][d]
// fused: colg>>8 selects output segment (Cb + seg*SZ); scale applies to seg 0 only.
__global__ __launch_bounds__(256) void mgemm_k(const __hip_bfloat16* __restrict__ A,
        int sA, int nk, const __hip_bfloat16* __restrict__ Wt, int sW,
        const float* __restrict__ bias, const float* __restrict__ pe,
        const __hip_bfloat16* __restrict__ resid, float* __restrict__ Cf,
        __hip_bfloat16* __restrict__ Cb, int relu, int fmt, float scale, int fused) {
    __shared__ __hip_bfloat16 As[64*72];
    __shared__ __hip_bfloat16 Ws[128*72];
    const int tid = threadIdx.x;
    const int w = tid >> 6, lane = tid & 63;
    const int uh = lane >> 5, l31 = lane & 31;
    const int wm = (w >> 1)*32, wn = (w & 1)*64;
    const size_t m0 = (size_t)blockIdx.x*64;
    const int n0 = blockIdx.y*128;

    f32x16 acc[2];
#pragma unroll
    for (int nt = 0; nt < 2; ++nt)
#pragma unroll
        for (int r = 0; r < 16; ++r) acc[nt][r] = 0.f;

    const int ra = tid >> 2, ca = (tid & 3)*16;
    const int rw = tid >> 1, cw = (tid & 1)*32;
    const __hip_bfloat16* ap = A  + (m0 + ra)*sA + ca;
    const __hip_bfloat16* wp = Wt + (size_t)(n0 + rw)*sW + cw;
    uint4 pa0 = *(const uint4*)(ap), pa1 = *(const uint4*)(ap + 8);
    uint4 pw0 = *(const uint4*)(wp),      pw1 = *(const uint4*)(wp + 8);
    uint4 pw2 = *(const uint4*)(wp + 16), pw3 = *(const uint4*)(wp + 24);
    for (int kt = 0; kt < nk; ++kt) {
        __syncthreads();
        *(uint4*)&As[ra*72 + ca]     = pa0;
        *(uint4*)&As[ra*72 + ca + 8] = pa1;
        *(uint4*)&Ws[rw*72 + cw]      = pw0;
        *(uint4*)&Ws[rw*72 + cw + 8]  = pw1;
        *(uint4*)&Ws[rw*72 + cw + 16] = pw2;
        *(uint4*)&Ws[rw*72 + cw + 24] = pw3;
        __syncthreads();
        if (kt + 1 < nk) {
            int ko = (kt + 1)*64;
            pa0 = *(const uint4*)(ap + ko);      pa1 = *(const uint4*)(ap + ko + 8);
            pw0 = *(const uint4*)(wp + ko);      pw1 = *(const uint4*)(wp + ko + 8);
            pw2 = *(const uint4*)(wp + ko + 16); pw3 = *(const uint4*)(wp + ko + 24);
        }
#pragma unroll
        for (int ks = 0; ks < 4; ++ks) {
            bf16x8 a0 = *(const bf16x8*)&As[(wm + l31)*72      + ks*16 + uh*8];
            bf16x8 b0 = *(const bf16x8*)&Ws[(wn + l31)*72      + ks*16 + uh*8];
            bf16x8 b1 = *(const bf16x8*)&Ws[(wn + 32 + l31)*72 + ks*16 + uh*8];
            acc[0] = __builtin_amdgcn_mfma_f32_32x32x16_bf16(a0, b0, acc[0], 0, 0, 0);
            acc[1] = __builtin_amdgcn_mfma_f32_32x32x16_bf16(a0, b1, acc[1], 0, 0, 0);
        }
    }

#pragma unroll
    for (int nt = 0; nt < 2; ++nt) {
        int colg = n0 + wn + nt*32 + l31;
        int seg = fused ? (colg >> 8) : 0;
        int c8  = fused ? (colg & 255) : colg;
        float sc = (seg == 0) ? scale : 1.0f;
        float bz = bias ? bias[c8] : 0.f;
        __hip_bfloat16* cb = Cb ? (Cb + (size_t)seg*SZ) : Cb;
#pragma unroll
        for (int r = 0; r < 16; ++r) {
            size_t mg = m0 + wm + (r & 3) + ((r >> 2) << 3) + 4*uh;
            float v = (acc[nt][r] + bz) * sc;
            if (pe)    v += pe[(mg & 31)*DM + c8];
            if (relu)  v = fmaxf(v, 0.f);
            if (resid) v += __bfloat162float(resid[mg*DM + c8]);
            size_t oidx;
            if (fmt == 1)
                oidx = (size_t)((mg & 31)*4 + (c8 >> 6))*65536 + (mg >> 5)*64 + (c8 & 63);
            else if (fmt == 2)
                oidx = ((size_t)(c8 >> 6)*NS + (mg >> 5))*2048 + (mg & 31)*64 + (c8 & 63);
            else
                oidx = mg*DM + c8;
            if (Cf) Cf[oidx] = v;
            if (cb) *(unsigned short*)&cb[oidx] = sbf(v);
        }
    }
}

// ================= T-attention + fused LayerNorm =============================
// Block n owns full rows (32 t x 256 d). Computes att, then LN(R+att) in one
// pass (cross-wave LDS reduction); writes ONLY the LN output (pre-LN sum dead).
union __align__(16) WLds { __hip_bfloat16 vt[64*40]; float ob[32*68]; };

__global__ __launch_bounds__(256) void attnT_k(const __hip_bfloat16* __restrict__ Q,
        const __hip_bfloat16* __restrict__ K, const __hip_bfloat16* __restrict__ V,
        const __hip_bfloat16* __restrict__ R, const float* __restrict__ g,
        const float* __restrict__ be, __hip_bfloat16* __restrict__ O) {
    __shared__ WLds sm4[4];
    __shared__ float redS[32][8];
    __shared__ float redQ[32][8];
    const int n = blockIdx.x;
    const int w = threadIdx.x >> 6, lane = threadIdx.x & 63;
    const int uh = lane >> 5, l31 = lane & 31;
    const size_t base = ((size_t)w*NS + n)*2048;   // head w, stock n

    bf16x8 kf[4], qf[4];
#pragma unroll
    for (int s = 0; s < 4; ++s) {
        kf[s] = *(const bf16x8*)(K + base + l31*64 + s*16 + uh*8);
        qf[s] = *(const bf16x8*)(Q + base + l31*64 + s*16 + uh*8);
    }
    __hip_bfloat16* vt = sm4[w].vt;
#pragma unroll
    for (int i = 0; i < 2; ++i) {
        int c = lane*2 + i;
        int dg = c >> 3, tg = c & 7;
        const ushort* vp = (const ushort*)(V + base + (tg*4)*64 + dg*4);
        ushort4 s0 = *(const ushort4*)(vp);
        ushort4 s1 = *(const ushort4*)(vp + 64);
        ushort4 s2 = *(const ushort4*)(vp + 128);
        ushort4 s3 = *(const ushort4*)(vp + 192);
        *(uint2*)&vt[(dg*4+0)*40 + tg*4] = make_uint2((unsigned)s0.x | ((unsigned)s1.x<<16),
                                                      (unsigned)s2.x | ((unsigned)s3.x<<16));
        *(uint2*)&vt[(dg*4+1)*40 + tg*4] = make_uint2((unsigned)s0.y | ((unsigned)s1.y<<16),
                                                      (unsigned)s2.y | ((unsigned)s3.y<<16));
        *(uint2*)&vt[(dg*4+2)*40 + tg*4] = make_uint2((unsigned)s0.z | ((unsigned)s1.z<<16),
                                                      (unsigned)s2.z | ((unsigned)s3.z<<16));
        *(uint2*)&vt[(dg*4+3)*40 + tg*4] = make_uint2((unsigned)s0.w | ((unsigned)s1.w<<16),
                                                      (unsigned)s2.w | ((unsigned)s3.w<<16));
    }

    f32x16 sa;
#pragma unroll
    for (int r = 0; r < 16; ++r) sa[r] = 0.f;
    sa = __builtin_amdgcn_mfma_f32_32x32x16_bf16(kf[0], qf[0], sa, 0, 0, 0);
    sa = __builtin_amdgcn_mfma_f32_32x32x16_bf16(kf[1], qf[1], sa, 0, 0, 0);
    sa = __builtin_amdgcn_mfma_f32_32x32x16_bf16(kf[2], qf[2], sa, 0, 0, 0);
    sa = __builtin_amdgcn_mfma_f32_32x32x16_bf16(kf[3], qf[3], sa, 0, 0, 0);

    float p[16], l = 0.f;
#pragma unroll
    for (int r = 0; r < 16; ++r) { p[r] = __builtin_amdgcn_exp2f(sa[r]); l += p[r]; }
    l += __shfl_xor(l, 32);

    bf16x8 pf[2];
#pragma unroll
    for (int s = 0; s < 2; ++s) {
        unsigned A0 = pkbf_fast(p[8*s+0], p[8*s+1]);
        unsigned A1 = pkbf_fast(p[8*s+2], p[8*s+3]);
        unsigned B0 = pkbf_fast(p[8*s+4], p[8*s+5]);
        unsigned B1 = pkbf_fast(p[8*s+6], p[8*s+7]);
        unsigned xA0 = (unsigned)__shfl_xor((int)A0, 32);
        unsigned xA1 = (unsigned)__shfl_xor((int)A1, 32);
        unsigned xB0 = (unsigned)__shfl_xor((int)B0, 32);
        unsigned xB1 = (unsigned)__shfl_xor((int)B1, 32);
        union { uint4 i; bf16x8 v; } cv;
        cv.i = make_uint4(uh ? xB0 : A0, uh ? xB1 : A1,
                          uh ? B0 : xA0, uh ? B1 : xA1);
        pf[s] = cv.v;
    }

    f32x16 oa[2];
#pragma unroll
    for (int c = 0; c < 2; ++c) {
#pragma unroll
        for (int r = 0; r < 16; ++r) oa[c][r] = 0.f;
        bf16x8 v0 = *(const bf16x8*)&vt[(c*32 + l31)*40 + uh*8];
        bf16x8 v1 = *(const bf16x8*)&vt[(c*32 + l31)*40 + 16 + uh*8];
        oa[c] = __builtin_amdgcn_mfma_f32_32x32x16_bf16(v0, pf[0], oa[c], 0, 0, 0);
        oa[c] = __builtin_amdgcn_mfma_f32_32x32x16_bf16(v1, pf[1], oa[c], 0, 0, 0);
    }

    // ---- transpose att into LDS, add residual, accumulate LN stats ----
    float invl = 1.0f / l;
    float* ob = sm4[w].ob;
#pragma unroll
    for (int c = 0; c < 2; ++c)
#pragma unroll
        for (int r = 0; r < 16; ++r) {
            int d = (r & 3) + ((r >> 2) << 3) + 4*uh + 32*c;
            ob[l31*68 + d] = oa[c][r] * invl;
        }
    int t = lane >> 1, d0 = (lane & 1)*32;
    size_t gi = ((size_t)n*ST + t)*DM + w*64 + d0;
    float ps = 0.f, pq = 0.f;
#pragma unroll
    for (int i = 0; i < 4; ++i) {
        uint4 rv = *(const uint4*)(R + gi + 8*i);
        float* s = &ob[t*68 + d0 + 8*i];
        float2 f0 = bf2x(rv.x), f1 = bf2x(rv.y), f2 = bf2x(rv.z), f3 = bf2x(rv.w);
        float v0 = f0.x + s[0], v1 = f0.y + s[1], v2 = f1.x + s[2], v3 = f1.y + s[3];
        float v4 = f2.x + s[4], v5 = f2.y + s[5], v6 = f3.x + s[6], v7 = f3.y + s[7];
        s[0] = v0; s[1] = v1; s[2] = v2; s[3] = v3;
        s[4] = v4; s[5] = v5; s[6] = v6; s[7] = v7;
        ps += v0+v1+v2+v3+v4+v5+v6+v7;
        pq += v0*v0+v1*v1+v2*v2+v3*v3+v4*v4+v5*v5+v6*v6+v7*v7;
    }
    redS[t][w*2 + (lane & 1)] = ps;
    redQ[t][w*2 + (lane & 1)] = pq;
    __syncthreads();
    float s8 = 0.f, q8 = 0.f;
#pragma unroll
    for (int i = 0; i < 8; ++i) { s8 += redS[t][i]; q8 += redQ[t][i]; }
    float mu = s8*(1.0f/DM);
    float var = q8*(1.0f/DM) - mu*mu;
    float rcp = rsqrtf(var + LN_EPS);
#pragma unroll
    for (int i = 0; i < 4; ++i) {
        const float* s = &ob[t*68 + d0 + 8*i];
        int cg = w*64 + d0 + 8*i;
        float4 g0 = *(const float4*)(g + cg),     g1 = *(const float4*)(g + cg + 4);
        float4 b0 = *(const float4*)(be + cg),    b1 = *(const float4*)(be + cg + 4);
        float o0 = (s[0]-mu)*rcp*g0.x + b0.x, o1 = (s[1]-mu)*rcp*g0.y + b0.y;
        float o2 = (s[2]-mu)*rcp*g0.z + b0.z, o3 = (s[3]-mu)*rcp*g0.w + b0.w;
        float o4 = (s[4]-mu)*rcp*g1.x + b1.x, o5 = (s[5]-mu)*rcp*g1.y + b1.y;
        float o6 = (s[6]-mu)*rcp*g1.z + b1.z, o7 = (s[7]-mu)*rcp*g1.w + b1.w;
        *(uint4*)(O + gi + 8*i) = make_uint4(pkbf_fast(o0, o1), pkbf_fast(o2, o3),
                                             pkbf_fast(o4, o5), pkbf_fast(o6, o7));
    }
}

// ================= S-attention: MFMA flash, sfmt QKV, XCD-swizzled ===========
union __align__(16) LdsS {
    struct { __hip_bfloat16 K[64*72]; __hip_bfloat16 Vt[64*72]; } s;
    float Ob[4][32*68];
};

__global__ __launch_bounds__(256) void attnS_k(const __hip_bfloat16* __restrict__ Qb,
        const __hip_bfloat16* __restrict__ Kb, const __hip_bfloat16* __restrict__ Vb,
        const __hip_bfloat16* __restrict__ R, __hip_bfloat16* __restrict__ O) {
    __shared__ LdsS sm;
    const int tt = blockIdx.x, h = blockIdx.y, qt = blockIdx.z;
    const int tid = threadIdx.x;
    const int w = tid >> 6, lane = tid & 63;
    const int uh = lane >> 5, l31 = lane & 31;
    const size_t hb = (size_t)(tt*4 + h)*65536;   // sfmt slice base

    bf16x8 qf[4];
    {
        const __hip_bfloat16* qp = Qb + hb + (size_t)(qt*128 + w*32 + l31)*64 + 8*uh;
        qf[0] = *(const bf16x8*)(qp);
        qf[1] = *(const bf16x8*)(qp + 16);
        qf[2] = *(const bf16x8*)(qp + 32);
        qf[3] = *(const bf16x8*)(qp + 48);
    }

    f32x16 oa[2];
#pragma unroll
    for (int c = 0; c < 2; ++c)
#pragma unroll
        for (int r = 0; r < 16; ++r) oa[c][r] = 0.f;
    float lrun = 0.f;

    for (int kt = 0; kt < 16; ++kt) {
        __syncthreads();
        {
            const __hip_bfloat16* kb = Kb + hb + (size_t)kt*4096;
#pragma unroll
            for (int i = 0; i < 2; ++i) {
                int c = tid*2 + i;
                int j = c >> 3, col = (c & 7)*8;
                *(uint4*)&sm.s.K[j*72 + col] = *(const uint4*)(kb + c*8);
            }
        }
        {
            int j0 = (tid & 15)*4, cb = (tid >> 4)*4;
            const ushort* vp = (const ushort*)(Vb + hb + (size_t)(kt*64 + j0)*64 + cb);
            ushort4 s0 = *(const ushort4*)(vp);
            ushort4 s1 = *(const ushort4*)(vp + 64);
            ushort4 s2 = *(const ushort4*)(vp + 128);
            ushort4 s3 = *(const ushort4*)(vp + 192);
            *(uint2*)&sm.s.Vt[(cb+0)*72 + j0] = make_uint2((unsigned)s0.x | ((unsigned)s1.x<<16),
                                                           (unsigned)s2.x | ((unsigned)s3.x<<16));
            *(uint2*)&sm.s.Vt[(cb+1)*72 + j0] = make_uint2((unsigned)s0.y | ((unsigned)s1.y<<16),
                                                           (unsigned)s2.y | ((unsigned)s3.y<<16));
            *(uint2*)&sm.s.Vt[(cb+2)*72 + j0] = make_uint2((unsigned)s0.z | ((unsigned)s1.z<<16),
                                                           (unsigned)s2.z | ((unsigned)s3.z<<16));
            *(uint2*)&sm.s.Vt[(cb+3)*72 + j0] = make_uint2((unsigned)s0.w | ((unsigned)s1.w<<16),
                                                           (unsigned)s2.w | ((unsigned)s3.w<<16));
        }
        __syncthreads();

        f32x16 sa[2];
#pragma unroll
        for (int ct = 0; ct < 2; ++ct) {
            f32x16 a2;
#pragma unroll
            for (int r = 0; r < 16; ++r) a2[r] = 0.f;
            const __hip_bfloat16* kb = &sm.s.K[(ct*32 + l31)*72 + 8*uh];
            a2 = __builtin_amdgcn_mfma_f32_32x32x16_bf16(*(const bf16x8*)(kb +  0), qf[0], a2, 0, 0, 0);
            a2 = __builtin_amdgcn_mfma_f32_32x32x16_bf16(*(const bf16x8*)(kb + 16), qf[1], a2, 0, 0, 0);
            a2 = __builtin_amdgcn_mfma_f32_32x32x16_bf16(*(const bf16x8*)(kb + 32), qf[2], a2, 0, 0, 0);
            a2 = __builtin_amdgcn_mfma_f32_32x32x16_bf16(*(const bf16x8*)(kb + 48), qf[3], a2, 0, 0, 0);
            sa[ct] = a2;
        }

        float p[32];
        float rs = 0.f;
#pragma unroll
        for (int ct = 0; ct < 2; ++ct)
#pragma unroll
            for (int r = 0; r < 16; ++r) {
                float e = __builtin_amdgcn_exp2f(sa[ct][r]);
                p[ct*16 + r] = e;
                rs += e;
            }
        rs += __shfl_xor(rs, 32);
        lrun += rs;

        bf16x8 bfr[4];
#pragma unroll
        for (int q = 0; q < 4; ++q) {
            int ct = q >> 1, b = (q & 1) << 3;
            unsigned A0 = pkbf_fast(p[ct*16+b+0], p[ct*16+b+1]);
            unsigned A1 = pkbf_fast(p[ct*16+b+2], p[ct*16+b+3]);
            unsigned B0 = pkbf_fast(p[ct*16+b+4], p[ct*16+b+5]);
            unsigned B1 = pkbf_fast(p[ct*16+b+6], p[ct*16+b+7]);
            unsigned xA0 = (unsigned)__shfl_xor((int)A0, 32);
            unsigned xA1 = (unsigned)__shfl_xor((int)A1, 32);
            unsigned xB0 = (unsigned)__shfl_xor((int)B0, 32);
            unsigned xB1 = (unsigned)__shfl_xor((int)B1, 32);
            union { uint4 i; bf16x8 v; } cv;
            cv.i = make_uint4(uh ? xB0 : A0, uh ? xB1 : A1,
                              uh ? B0 : xA0, uh ? B1 : xA1);
            bfr[q] = cv.v;
        }

#pragma unroll
        for (int c = 0; c < 2; ++c) {
            const __hip_bfloat16* vb = &sm.s.Vt[(c*32 + l31)*72 + 8*uh];
            oa[c] = __builtin_amdgcn_mfma_f32_32x32x16_bf16(*(const bf16x8*)(vb +  0), bfr[0], oa[c], 0, 0, 0);
            oa[c] = __builtin_amdgcn_mfma_f32_32x32x16_bf16(*(const bf16x8*)(vb + 16), bfr[1], oa[c], 0, 0, 0);
            oa[c] = __builtin_amdgcn_mfma_f32_32x32x16_bf16(*(const bf16x8*)(vb + 32), bfr[2], oa[c], 0, 0, 0);
            oa[c] = __builtin_amdgcn_mfma_f32_32x32x16_bf16(*(const bf16x8*)(vb + 48), bfr[3], oa[c], 0, 0, 0);
        }
    }

    __syncthreads();
    float invl = 1.0f / lrun;
    float* ob = sm.Ob[w];
#pragma unroll
    for (int c = 0; c < 2; ++c)
#pragma unroll
        for (int r = 0; r < 16; ++r) {
            int d = (r & 3) + ((r >> 2) << 3) + 4*uh + 32*c;
            ob[l31*68 + d] = oa[c][r] * invl;
        }
#pragma unroll
    for (int pp = 0; pp < 2; ++pp) {
        int qr = pp*16 + (lane >> 2);
        int dc = (lane & 3) << 4;
        size_t gi = ((size_t)(qt*128 + w*32 + qr)*ST + tt)*DM + h*64 + dc;
#pragma unroll
        for (int i = 0; i < 2; ++i) {
            uint4 rv = *(const uint4*)(R + gi + 8*i);
            *(uint4*)(O + gi + 8*i) = addpk(rv, &ob[qr*68 + dc + 8*i]);
        }
    }
}

// ================= temporal pooling + decoder ================================
__global__ __launch_bounds__(256) void final_k(const __hip_bfloat16* __restrict__ H,
        const float* __restrict__ HH, const float* __restrict__ dw,
        const float* __restrict__ db, float* __restrict__ out) {
    int n = blockIdx.x, d = threadIdx.x;
    int w = d >> 6, lane = d & 63;
    __shared__ float lam[ST];
    __shared__ float red[8];
    const float* hh = HH + (size_t)n*ST*DM;
    float4 qd = *(const float4*)(hh + 31*DM + lane*4);
#pragma unroll
    for (int i = 0; i < 8; ++i) {
        int t = w*8 + i;
        float4 h4 = *(const float4*)(hh + t*DM + lane*4);
        float s = wave_sum(h4.x*qd.x + h4.y*qd.y + h4.z*qd.z + h4.w*qd.w);
        if (lane == 0) lam[t] = s;
    }
    __syncthreads();
    float mx = -1e30f;
#pragma unroll
    for (int t = 0; t < ST; ++t) mx = fmaxf(mx, lam[t]);
    float sum = 0.f;
#pragma unroll
    for (int t = 0; t < ST; ++t) sum += __expf(lam[t]-mx);
    float acc = 0.f;
    const __hip_bfloat16* hrow = H + (size_t)n*ST*DM;
#pragma unroll
    for (int t = 0; t < ST; ++t)
        acc += __expf(lam[t]-mx) * __bfloat162float(hrow[t*DM + d]);
    acc /= sum;
    float p0 = wave_sum(acc * dw[2*d+0]);
    float p1 = wave_sum(acc * dw[2*d+1]);
    if (lane == 0) { red[w] = p0; red[4 + w] = p1; }
    __syncthreads();
    if (d == 0) {
        float r0 = red[0]+red[1]+red[2]+red[3] + db[0];
        float r1 = red[4]+red[5]+red[6]+red[7] + db[1];
        out[(size_t)n*2+0] = r0;           out[(size_t)n*2+1] = r1;
        out[2048 + (size_t)n*2+0] = r0;    out[2048 + (size_t)n*2+1] = r1;
        out[4096 + (size_t)n*2+0] = r0;    out[4096 + (size_t)n*2+1] = r1;
        if (n == 0) out[6144] = 0.f;
    }
}

extern "C" void kernel_launch(void* const* d_in, const int* in_sizes, int n_in,
                              void* d_out, int out_size, void* d_ws, size_t ws_size,
                              hipStream_t stream) {
    const float* x     = (const float*)d_in[0];
    const float* emb_w = (const float*)d_in[5];
    const float* emb_b = (const float*)d_in[6];
    const float* pe    = (const float*)d_in[7];
    const float* t_g1  = (const float*)d_in[11];
    const float* t_b1  = (const float*)d_in[12];
    const float* t_g2  = (const float*)d_in[13];
    const float* t_b2  = (const float*)d_in[14];
    const float* t_bb1 = (const float*)d_in[16];
    const float* t_bb2 = (const float*)d_in[18];
    const float* s_g1  = (const float*)d_in[22];
    const float* s_b1  = (const float*)d_in[23];
    const float* s_g2  = (const float*)d_in[24];
    const float* s_b2  = (const float*)d_in[25];
    const float* s_bb1 = (const float*)d_in[27];
    const float* s_bb2 = (const float*)d_in[29];
    const float* dec_w = (const float*)d_in[31];
    const float* dec_b = (const float*)d_in[32];
    float* out = (float*)d_out;

    // ---- workspace layout (~126 MB) ----
    float* F0 = (float*)d_ws;                       // 32 MB (hh, fp32)
    __hip_bfloat16* B0 = (__hip_bfloat16*)(F0 + SZ);// 16 MB each
    __hip_bfloat16* B1 = B0 + SZ;
    __hip_bfloat16* B2 = B1 + SZ;                   // B2,B3,B4 contiguous (fused QKV)
    __hip_bfloat16* B3 = B2 + SZ;
    __hip_bfloat16* B4 = B3 + SZ;
    __hip_bfloat16* WT  = B4 + SZ;                  // 11 x 256x256
    __hip_bfloat16* WTE = WT + (size_t)11*DM*DM;    // 256x192
    __hip_bfloat16* XB  = WTE + (size_t)DM*KE;      // 32768x192

    // ---- conversions ----
    cvtx_k<<<ROWS*KE/256, 256, 0, stream>>>(x, XB);
    WPack wp;
    const int widx[11] = {8, 9, 10, 15, 17, 19, 20, 21, 26, 28, 30};
    for (int i = 0; i < 11; ++i) {
        wp.s[i] = (const float*)d_in[widx[i]];
        wp.d[i] = WT + (size_t)i*DM*DM;
    }
    cvtw_k<<<dim3(4, 4, 11), 256, 0, stream>>>(wp);
    cvte_k<<<DM, 192, 0, stream>>>(emb_w, WTE);

    dim3 gg(ROWS/64, 2);                             // std gemm: 1024 blocks
    dim3 gq(ROWS/64, 6);                             // fused QKV: 3072 blocks
    __hip_bfloat16* WqT = WT;                        // Wq|Wk|Wv contiguous
    __hip_bfloat16* W1  = WT + (size_t)3*DM*DM;
    __hip_bfloat16* W2  = WT + (size_t)4*DM*DM;
    __hip_bfloat16* SWq = WT + (size_t)5*DM*DM;      // SWq|SWk|SWv contiguous
    __hip_bfloat16* SW1 = WT + (size_t)8*DM*DM;
    __hip_bfloat16* SW2 = WT + (size_t)9*DM*DM;
    __hip_bfloat16* WTA = WT + (size_t)10*DM*DM;

    // ---- embed + PE ----
    mgemm_k<<<gg, 256, 0, stream>>>(XB, KE, 3, WTE, KE, emb_b, pe, nullptr, nullptr, B0, 0, 0, 1.f, 0);
    // ---- TAttention block ----
    ln_k<<<ROWS/4, 256, 0, stream>>>(B0, t_g1, t_b1, B1);                 // B1 = xn
    mgemm_k<<<gq, 256, 0, stream>>>(B1, 256, 4, WqT, 256, nullptr, nullptr, nullptr, nullptr, B2, 0, 2, LOG2E, 1);
    attnT_k<<<NS, 256, 0, stream>>>(B2, B3, B4, B1, t_g2, t_b2, B1);      // B1 = LN(xn+att) = xt
    mgemm_k<<<gg, 256, 0, stream>>>(B1, 256, 4, W1, 256, t_bb1, nullptr, nullptr, nullptr, B2, 1, 0, 1.f, 0);
    mgemm_k<<<gg, 256, 0, stream>>>(B2, 256, 4, W2, 256, t_bb2, nullptr, B1, nullptr, B0, 0, 0, 1.f, 0);  // B0 = h1
    // ---- SAttention block ----
    ln_k<<<ROWS/4, 256, 0, stream>>>(B0, s_g1, s_b1, B1);                 // B1 = xn2
    mgemm_k<<<gq, 256, 0, stream>>>(B1, 256, 4, SWq, 256, nullptr, nullptr, nullptr, nullptr, B2, 0, 1, 0.125f*LOG2E, 1);
    attnS_k<<<dim3(32, 4, 8), 256, 0, stream>>>(B2, B3, B4, B1, B0);      // B0 = xn2+att
    ln_k<<<ROWS/4, 256, 0, stream>>>(B0, s_g2, s_b2, B1);                 // B1 = xt2
    mgemm_k<<<gg, 256, 0, stream>>>(B1, 256, 4, SW1, 256, s_bb1, nullptr, nullptr, nullptr, B2, 1, 0, 1.f, 0);
    mgemm_k<<<gg, 256, 0, stream>>>(B2, 256, 4, SW2, 256, s_bb2, nullptr, B1, nullptr, B0, 0, 0, 1.f, 0); // B0 = h2
    // ---- temporal attention + decoder ----
    mgemm_k<<<gg, 256, 0, stream>>>(B0, 256, 4, WTA, 256, nullptr, nullptr, nullptr, F0, nullptr, 0, 0, 1.f, 0);  // F0 = hh (fp32)
    final_k<<<NS, 256, 0, stream>>>(B0, F0, dec_w, dec_b, out);
}

// Round 11
// 384.380 us; speedup vs baseline: 1.9716x; 1.3004x over previous
//
#include <hip/hip_runtime.h>
#include <hip/hip_bf16.h>
#include <math.h>

#define NS 1024
#define ST 32
#define DF 158
#define DM 256
#define KE 192                 // embed K padded to BK=64 multiple
#define ROWS (NS*ST)           // 32768
#define SZ ((size_t)ROWS*DM)   // 8388608 elems
#define LN_EPS 1e-5f
#define LOG2E 1.44269504088896f

typedef __attribute__((ext_vector_type(8)))  __bf16 bf16x8;
typedef __attribute__((ext_vector_type(16))) float  f32x16;

__device__ __forceinline__ float wave_sum(float v) {
#pragma unroll
    for (int o = 32; o > 0; o >>= 1) v += __shfl_xor(v, o);
    return v;
}

// accurate RNE pack (weight conversion only)
__device__ __forceinline__ unsigned pkbf(float a, float b) {
    __hip_bfloat16 ha = __float2bfloat16(a), hb = __float2bfloat16(b);
    unsigned short ua, ub;
    __builtin_memcpy(&ua, &ha, 2); __builtin_memcpy(&ub, &hb, 2);
    return (unsigned)ua | ((unsigned)ub << 16);
}

// fast pack: round-half-up (3-5 VALU ops). Differs from RNE only on exact ties.
__device__ __forceinline__ unsigned pkbf_fast(float a, float b) {
    unsigned ua = __float_as_uint(a) + 0x8000u;
    unsigned ub = __float_as_uint(b) + 0x8000u;
    return (ua >> 16) | (ub & 0xffff0000u);
}

__device__ __forceinline__ unsigned short sbf(float a) {
    return (unsigned short)((__float_as_uint(a) + 0x8000u) >> 16);
}

__device__ __forceinline__ float2 bf2x(unsigned u) {
    union { unsigned i; float f; } a, b;
    a.i = u << 16; b.i = u & 0xffff0000u;
    return make_float2(a.f, b.f);   // x = low element, y = high element
}

// add 8 floats (s[0..7]) onto a uint4 of 8 packed bf16, repack (fast)
__device__ __forceinline__ uint4 addpk(uint4 rv, const float* s) {
    float2 f0 = bf2x(rv.x), f1 = bf2x(rv.y), f2 = bf2x(rv.z), f3 = bf2x(rv.w);
    return make_uint4(pkbf_fast(f0.x + s[0], f0.y + s[1]),
                      pkbf_fast(f1.x + s[2], f1.y + s[3]),
                      pkbf_fast(f2.x + s[4], f2.y + s[5]),
                      pkbf_fast(f3.x + s[6], f3.y + s[7]));
}

// elementwise bf16x8 + bf16x8 -> bf16x8 (fp32 math, fast repack)
__device__ __forceinline__ uint4 addbk(uint4 a, uint4 b) {
    float2 a0 = bf2x(a.x), a1 = bf2x(a.y), a2 = bf2x(a.z), a3 = bf2x(a.w);
    float2 b0 = bf2x(b.x), b1 = bf2x(b.y), b2 = bf2x(b.z), b3 = bf2x(b.w);
    return make_uint4(pkbf_fast(a0.x + b0.x, a0.y + b0.y),
                      pkbf_fast(a1.x + b1.x, a1.y + b1.y),
                      pkbf_fast(a2.x + b2.x, a2.y + b2.y),
                      pkbf_fast(a3.x + b3.x, a3.y + b3.y));
}

// ================= conversion kernels (run every launch; idempotent) =========
__global__ __launch_bounds__(256) void cvtx_k(const float* __restrict__ x,
        __hip_bfloat16* __restrict__ xb) {
    int idx = blockIdx.x*256 + threadIdx.x;          // < 32768*192
    int r = idx / KE, c = idx - r*KE;
    float v = (c < DF) ? x[(size_t)r*DF + c] : 0.f;
    xb[idx] = __float2bfloat16(v);
}

struct WPack { const float* s[11]; __hip_bfloat16* d[11]; };

__global__ __launch_bounds__(256) void cvtw_k(WPack wp) {
    const float* W = wp.s[blockIdx.z];
    __hip_bfloat16* Wt = wp.d[blockIdx.z];
    __shared__ float t[64][65];
    int bi = blockIdx.x*64, bj = blockIdx.y*64;
    int r = threadIdx.x >> 2, c0 = (threadIdx.x & 3) * 16;
#pragma unroll
    for (int i = 0; i < 16; i += 4) {
        float4 v = *(const float4*)(W + (size_t)(bi + r)*DM + bj + c0 + i);
        t[r][c0+i+0] = v.x; t[r][c0+i+1] = v.y;
        t[r][c0+i+2] = v.z; t[r][c0+i+3] = v.w;
    }
    __syncthreads();
    unsigned u[8];
#pragma unroll
    for (int i = 0; i < 8; ++i) u[i] = pkbf(t[c0+2*i][r], t[c0+2*i+1][r]);
    __hip_bfloat16* op = Wt + (size_t)(bj + r)*DM + bi + c0;
    *(uint4*)(op)     = make_uint4(u[0], u[1], u[2], u[3]);
    *(uint4*)(op + 8) = make_uint4(u[4], u[5], u[6], u[7]);
}

__global__ __launch_bounds__(192) void cvte_k(const float* __restrict__ W,
        __hip_bfloat16* __restrict__ Wt) {
    int n = blockIdx.x, t = threadIdx.x;   // t < 192
    float v = (t < DF) ? W[(size_t)t*DM + n] : 0.f;
    Wt[(size_t)n*KE + t] = __float2bfloat16(v);
}

// ================= LayerNorm: bf16 in -> bf16 out, one wave per row =========
__global__ __launch_bounds__(256) void ln_k(const __hip_bfloat16* __restrict__ a,
        const float* __restrict__ g, const float* __restrict__ be,
        __hip_bfloat16* __restrict__ outb) {
    int w = threadIdx.x >> 6, lane = threadIdx.x & 63;
    size_t r = (size_t)blockIdx.x*4 + w;
    uint2 raw = *(const uint2*)(a + r*DM + lane*4);
    float2 v01 = bf2x(raw.x), v23 = bf2x(raw.y);
    float mu = wave_sum(v01.x+v01.y+v23.x+v23.y) * (1.0f/DM);
    float c0 = v01.x-mu, c1 = v01.y-mu, c2 = v23.x-mu, c3 = v23.y-mu;
    float var = wave_sum(c0*c0 + c1*c1 + c2*c2 + c3*c3) * (1.0f/DM);
    float rs = rsqrtf(var + LN_EPS);
    float4 g4 = *(const float4*)(g + lane*4);
    float4 b4 = *(const float4*)(be + lane*4);
    float o0 = c0*rs*g4.x + b4.x, o1 = c1*rs*g4.y + b4.y;
    float o2 = c2*rs*g4.z + b4.z, o3 = c3*rs*g4.w + b4.w;
    *(uint2*)(outb + r*DM + lane*4) = make_uint2(pkbf_fast(o0, o1), pkbf_fast(o2, o3));
}

// ================= MFMA GEMM: 64x128 tile, BK=64 ============================
// fmt: 0 = std [row][col]; 1 = sfmt [(t*4+h)][stock][d]; 2 = tfmt [h][stock][t][d]
// fused: colg>>8 selects output segment (Cb + seg*SZ); scale applies to seg 0 only.
// bf16 output path uses LDS-transpose epilogue -> uint4 stores (128B bursts).
union __align__(16) GLds {
    struct { __hip_bfloat16 As[64*72]; __hip_bfloat16 Ws[128*72]; } s;   // 27648 B
    __hip_bfloat16 Ob[64*136];                                          // 17408 B
};

__global__ __launch_bounds__(256) void mgemm_k(const __hip_bfloat16* __restrict__ A,
        int sA, int nk, const __hip_bfloat16* __restrict__ Wt, int sW,
        const float* __restrict__ bias, const float* __restrict__ pe,
        const __hip_bfloat16* __restrict__ resid, float* __restrict__ Cf,
        __hip_bfloat16* __restrict__ Cb, int relu, int fmt, float scale, int fused) {
    __shared__ GLds gsm;
    const int tid = threadIdx.x;
    const int w = tid >> 6, lane = tid & 63;
    const int uh = lane >> 5, l31 = lane & 31;
    const int wm = (w >> 1)*32, wn = (w & 1)*64;
    const size_t m0 = (size_t)blockIdx.x*64;
    const int n0 = blockIdx.y*128;

    f32x16 acc[2];
#pragma unroll
    for (int nt = 0; nt < 2; ++nt)
#pragma unroll
        for (int r = 0; r < 16; ++r) acc[nt][r] = 0.f;

    const int ra = tid >> 2, ca = (tid & 3)*16;
    const int rw = tid >> 1, cw = (tid & 1)*32;
    const __hip_bfloat16* ap = A  + (m0 + ra)*sA + ca;
    const __hip_bfloat16* wp = Wt + (size_t)(n0 + rw)*sW + cw;
    uint4 pa0 = *(const uint4*)(ap), pa1 = *(const uint4*)(ap + 8);
    uint4 pw0 = *(const uint4*)(wp),      pw1 = *(const uint4*)(wp + 8);
    uint4 pw2 = *(const uint4*)(wp + 16), pw3 = *(const uint4*)(wp + 24);
    for (int kt = 0; kt < nk; ++kt) {
        __syncthreads();
        *(uint4*)&gsm.s.As[ra*72 + ca]     = pa0;
        *(uint4*)&gsm.s.As[ra*72 + ca + 8] = pa1;
        *(uint4*)&gsm.s.Ws[rw*72 + cw]      = pw0;
        *(uint4*)&gsm.s.Ws[rw*72 + cw + 8]  = pw1;
        *(uint4*)&gsm.s.Ws[rw*72 + cw + 16] = pw2;
        *(uint4*)&gsm.s.Ws[rw*72 + cw + 24] = pw3;
        __syncthreads();
        if (kt + 1 < nk) {
            int ko = (kt + 1)*64;
            pa0 = *(const uint4*)(ap + ko);      pa1 = *(const uint4*)(ap + ko + 8);
            pw0 = *(const uint4*)(wp + ko);      pw1 = *(const uint4*)(wp + ko + 8);
            pw2 = *(const uint4*)(wp + ko + 16); pw3 = *(const uint4*)(wp + ko + 24);
        }
#pragma unroll
        for (int ks = 0; ks < 4; ++ks) {
            bf16x8 a0 = *(const bf16x8*)&gsm.s.As[(wm + l31)*72      + ks*16 + uh*8];
            bf16x8 b0 = *(const bf16x8*)&gsm.s.Ws[(wn + l31)*72      + ks*16 + uh*8];
            bf16x8 b1 = *(const bf16x8*)&gsm.s.Ws[(wn + 32 + l31)*72 + ks*16 + uh*8];
            acc[0] = __builtin_amdgcn_mfma_f32_32x32x16_bf16(a0, b0, acc[0], 0, 0, 0);
            acc[1] = __builtin_amdgcn_mfma_f32_32x32x16_bf16(a0, b1, acc[1], 0, 0, 0);
        }
    }

    if (Cf) {
        // fp32 output path (hh gemm): scalar fp32 stores (128B/wave-inst)
#pragma unroll
        for (int nt = 0; nt < 2; ++nt) {
            int colg = n0 + wn + nt*32 + l31;
            float bz = bias ? bias[colg] : 0.f;
#pragma unroll
            for (int r = 0; r < 16; ++r) {
                size_t mg = m0 + wm + (r & 3) + ((r >> 2) << 3) + 4*uh;
                float v = (acc[nt][r] + bz) * scale;
                if (pe)   v += pe[(mg & 31)*DM + colg];
                if (relu) v = fmaxf(v, 0.f);
                Cf[mg*DM + colg] = v;
            }
        }
    } else {
        // bf16 path: transpose through LDS, wide uint4 stores
        __syncthreads();   // all waves done reading As/Ws
#pragma unroll
        for (int nt = 0; nt < 2; ++nt) {
            int col = wn + nt*32 + l31;
            int colg = n0 + col;
            int c8  = fused ? (colg & 255) : colg;
            float sc = (fused && (colg >> 8)) ? 1.0f : scale;
            float bz = bias ? bias[c8] : 0.f;
#pragma unroll
            for (int r = 0; r < 16; ++r) {
                int mrow = wm + (r & 3) + ((r >> 2) << 3) + 4*uh;
                float v = (acc[nt][r] + bz) * sc;
                if (pe)   v += pe[((m0 + mrow) & 31)*DM + c8];
                if (relu) v = fmaxf(v, 0.f);
                *(unsigned short*)&gsm.Ob[mrow*136 + col] = sbf(v);
            }
        }
        __syncthreads();
        int m = tid >> 2;
        size_t mg = m0 + m;
#pragma unroll
        for (int i = 0; i < 4; ++i) {
            int ncol = ((tid & 3) + 4*i)*8;
            uint4 val = *(const uint4*)&gsm.Ob[m*136 + ncol];
            int colg = n0 + ncol;
            int seg = fused ? (colg >> 8) : 0;
            int c8  = fused ? (colg & 255) : colg;
            if (resid) val = addbk(val, *(const uint4*)(resid + mg*DM + c8));
            size_t oidx;
            if (fmt == 1)
                oidx = (size_t)((mg & 31)*4 + (c8 >> 6))*65536 + (mg >> 5)*64 + (c8 & 63);
            else if (fmt == 2)
                oidx = ((size_t)(c8 >> 6)*NS + (mg >> 5))*2048 + (mg & 31)*64 + (c8 & 63);
            else
                oidx = mg*DM + c8;
            *(uint4*)&(Cb + (size_t)seg*SZ)[oidx] = val;
        }
    }
}

// ================= T-attention + fused LayerNorm =============================
union __align__(16) WLds { __hip_bfloat16 vt[64*40]; float ob[32*68]; };

__global__ __launch_bounds__(256) void attnT_k(const __hip_bfloat16* __restrict__ Q,
        const __hip_bfloat16* __restrict__ K, const __hip_bfloat16* __restrict__ V,
        const __hip_bfloat16* __restrict__ R, const float* __restrict__ g,
        const float* __restrict__ be, __hip_bfloat16* __restrict__ O) {
    __shared__ WLds sm4[4];
    __shared__ float redS[32][8];
    __shared__ float redQ[32][8];
    const int n = blockIdx.x;
    const int w = threadIdx.x >> 6, lane = threadIdx.x & 63;
    const int uh = lane >> 5, l31 = lane & 31;
    const size_t base = ((size_t)w*NS + n)*2048;   // head w, stock n

    bf16x8 kf[4], qf[4];
#pragma unroll
    for (int s = 0; s < 4; ++s) {
        kf[s] = *(const bf16x8*)(K + base + l31*64 + s*16 + uh*8);
        qf[s] = *(const bf16x8*)(Q + base + l31*64 + s*16 + uh*8);
    }
    __hip_bfloat16* vt = sm4[w].vt;
#pragma unroll
    for (int i = 0; i < 2; ++i) {
        int c = lane*2 + i;
        int dg = c >> 3, tg = c & 7;
        const ushort* vp = (const ushort*)(V + base + (tg*4)*64 + dg*4);
        ushort4 s0 = *(const ushort4*)(vp);
        ushort4 s1 = *(const ushort4*)(vp + 64);
        ushort4 s2 = *(const ushort4*)(vp + 128);
        ushort4 s3 = *(const ushort4*)(vp + 192);
        *(uint2*)&vt[(dg*4+0)*40 + tg*4] = make_uint2((unsigned)s0.x | ((unsigned)s1.x<<16),
                                                      (unsigned)s2.x | ((unsigned)s3.x<<16));
        *(uint2*)&vt[(dg*4+1)*40 + tg*4] = make_uint2((unsigned)s0.y | ((unsigned)s1.y<<16),
                                                      (unsigned)s2.y | ((unsigned)s3.y<<16));
        *(uint2*)&vt[(dg*4+2)*40 + tg*4] = make_uint2((unsigned)s0.z | ((unsigned)s1.z<<16),
                                                      (unsigned)s2.z | ((unsigned)s3.z<<16));
        *(uint2*)&vt[(dg*4+3)*40 + tg*4] = make_uint2((unsigned)s0.w | ((unsigned)s1.w<<16),
                                                      (unsigned)s2.w | ((unsigned)s3.w<<16));
    }

    f32x16 sa;
#pragma unroll
    for (int r = 0; r < 16; ++r) sa[r] = 0.f;
    sa = __builtin_amdgcn_mfma_f32_32x32x16_bf16(kf[0], qf[0], sa, 0, 0, 0);
    sa = __builtin_amdgcn_mfma_f32_32x32x16_bf16(kf[1], qf[1], sa, 0, 0, 0);
    sa = __builtin_amdgcn_mfma_f32_32x32x16_bf16(kf[2], qf[2], sa, 0, 0, 0);
    sa = __builtin_amdgcn_mfma_f32_32x32x16_bf16(kf[3], qf[3], sa, 0, 0, 0);

    float p[16], l = 0.f;
#pragma unroll
    for (int r = 0; r < 16; ++r) { p[r] = __builtin_amdgcn_exp2f(sa[r]); l += p[r]; }
    l += __shfl_xor(l, 32);

    bf16x8 pf[2];
#pragma unroll
    for (int s = 0; s < 2; ++s) {
        unsigned A0 = pkbf_fast(p[8*s+0], p[8*s+1]);
        unsigned A1 = pkbf_fast(p[8*s+2], p[8*s+3]);
        unsigned B0 = pkbf_fast(p[8*s+4], p[8*s+5]);
        unsigned B1 = pkbf_fast(p[8*s+6], p[8*s+7]);
        unsigned xA0 = (unsigned)__shfl_xor((int)A0, 32);
        unsigned xA1 = (unsigned)__shfl_xor((int)A1, 32);
        unsigned xB0 = (unsigned)__shfl_xor((int)B0, 32);
        unsigned xB1 = (unsigned)__shfl_xor((int)B1, 32);
        union { uint4 i; bf16x8 v; } cv;
        cv.i = make_uint4(uh ? xB0 : A0, uh ? xB1 : A1,
                          uh ? B0 : xA0, uh ? B1 : xA1);
        pf[s] = cv.v;
    }

    f32x16 oa[2];
#pragma unroll
    for (int c = 0; c < 2; ++c) {
#pragma unroll
        for (int r = 0; r < 16; ++r) oa[c][r] = 0.f;
        bf16x8 v0 = *(const bf16x8*)&vt[(c*32 + l31)*40 + uh*8];
        bf16x8 v1 = *(const bf16x8*)&vt[(c*32 + l31)*40 + 16 + uh*8];
        oa[c] = __builtin_amdgcn_mfma_f32_32x32x16_bf16(v0, pf[0], oa[c], 0, 0, 0);
        oa[c] = __builtin_amdgcn_mfma_f32_32x32x16_bf16(v1, pf[1], oa[c], 0, 0, 0);
    }

    // ---- transpose att into LDS, add residual, accumulate LN stats ----
    float invl = 1.0f / l;
    float* ob = sm4[w].ob;
#pragma unroll
    for (int c = 0; c < 2; ++c)
#pragma unroll
        for (int r = 0; r < 16; ++r) {
            int d = (r & 3) + ((r >> 2) << 3) + 4*uh + 32*c;
            ob[l31*68 + d] = oa[c][r] * invl;
        }
    int t = lane >> 1, d0 = (lane & 1)*32;
    size_t gi = ((size_t)n*ST + t)*DM + w*64 + d0;
    float ps = 0.f, pq = 0.f;
#pragma unroll
    for (int i = 0; i < 4; ++i) {
        uint4 rv = *(const uint4*)(R + gi + 8*i);
        float* s = &ob[t*68 + d0 + 8*i];
        float2 f0 = bf2x(rv.x), f1 = bf2x(rv.y), f2 = bf2x(rv.z), f3 = bf2x(rv.w);
        float v0 = f0.x + s[0], v1 = f0.y + s[1], v2 = f1.x + s[2], v3 = f1.y + s[3];
        float v4 = f2.x + s[4], v5 = f2.y + s[5], v6 = f3.x + s[6], v7 = f3.y + s[7];
        s[0] = v0; s[1] = v1; s[2] = v2; s[3] = v3;
        s[4] = v4; s[5] = v5; s[6] = v6; s[7] = v7;
        ps += v0+v1+v2+v3+v4+v5+v6+v7;
        pq += v0*v0+v1*v1+v2*v2+v3*v3+v4*v4+v5*v5+v6*v6+v7*v7;
    }
    redS[t][w*2 + (lane & 1)] = ps;
    redQ[t][w*2 + (lane & 1)] = pq;
    __syncthreads();
    float s8 = 0.f, q8 = 0.f;
#pragma unroll
    for (int i = 0; i < 8; ++i) { s8 += redS[t][i]; q8 += redQ[t][i]; }
    float mu = s8*(1.0f/DM);
    float var = q8*(1.0f/DM) - mu*mu;
    float rcp = rsqrtf(var + LN_EPS);
#pragma unroll
    for (int i = 0; i < 4; ++i) {
        const float* s = &ob[t*68 + d0 + 8*i];
        int cg = w*64 + d0 + 8*i;
        float4 g0 = *(const float4*)(g + cg),     float4g1 = *(const float4*)(g + cg + 4);
        float4 b0 = *(const float4*)(be + cg),    b1 = *(const float4*)(be + cg + 4);
        float o0 = (s[0]-mu)*rcp*g0.x + b0.x, o1 = (s[1]-mu)*rcp*g0.y + b0.y;
        float o2 = (s[2]-mu)*rcp*g0.z + b0.z, o3 = (s[3]-mu)*rcp*g0.w + b0.w;
        float o4 = (s[4]-mu)*rcp*float4g1.x + b1.x, o5 = (s[5]-mu)*rcp*float4g1.y + b1.y;
        float o6 = (s[6]-mu)*rcp*float4g1.z + b1.z, o7 = (s[7]-mu)*rcp*float4g1.w + b1.w;
        *(uint4*)(O + gi + 8*i) = make_uint4(pkbf_fast(o0, o1), pkbf_fast(o2, o3),
                                             pkbf_fast(o4, o5), pkbf_fast(o6, o7));
    }
}

// ================= S-attention: MFMA flash, sfmt QKV, XCD-swizzled ===========
union __align__(16) LdsS {
    struct { __hip_bfloat16 K[64*72]; __hip_bfloat16 Vt[64*72]; } s;
    float Ob[4][32*68];
};

__global__ __launch_bounds__(256) void attnS_k(const __hip_bfloat16* __restrict__ Qb,
        const __hip_bfloat16* __restrict__ Kb, const __hip_bfloat16* __restrict__ Vb,
        const __hip_bfloat16* __restrict__ R, __hip_bfloat16* __restrict__ O) {
    __shared__ LdsS sm;
    const int tt = blockIdx.x, h = blockIdx.y, qt = blockIdx.z;
    const int tid = threadIdx.x;
    const int w = tid >> 6, lane = tid & 63;
    const int uh = lane >> 5, l31 = lane & 31;
    const size_t hb = (size_t)(tt*4 + h)*65536;   // sfmt slice base

    bf16x8 qf[4];
    {
        const __hip_bfloat16* qp = Qb + hb + (size_t)(qt*128 + w*32 + l31)*64 + 8*uh;
        qf[0] = *(const bf16x8*)(qp);
        qf[1] = *(const bf16x8*)(qp + 16);
        qf[2] = *(const bf16x8*)(qp + 32);
        qf[3] = *(const bf16x8*)(qp + 48);
    }

    f32x16 oa[2];
#pragma unroll
    for (int c = 0; c < 2; ++c)
#pragma unroll
        for (int r = 0; r < 16; ++r) oa[c][r] = 0.f;
    float lrun = 0.f;

    for (int kt = 0; kt < 16; ++kt) {
        __syncthreads();
        {
            const __hip_bfloat16* kb = Kb + hb + (size_t)kt*4096;
#pragma unroll
            for (int i = 0; i < 2; ++i) {
                int c = tid*2 + i;
                int j = c >> 3, col = (c & 7)*8;
                *(uint4*)&sm.s.K[j*72 + col] = *(const uint4*)(kb + c*8);
            }
        }
        {
            int j0 = (tid & 15)*4, cb = (tid >> 4)*4;
            const ushort* vp = (const ushort*)(Vb + hb + (size_t)(kt*64 + j0)*64 + cb);
            ushort4 s0 = *(const ushort4*)(vp);
            ushort4 s1 = *(const ushort4*)(vp + 64);
            ushort4 s2 = *(const ushort4*)(vp + 128);
            ushort4 s3 = *(const ushort4*)(vp + 192);
            *(uint2*)&sm.s.Vt[(cb+0)*72 + j0] = make_uint2((unsigned)s0.x | ((unsigned)s1.x<<16),
                                                           (unsigned)s2.x | ((unsigned)s3.x<<16));
            *(uint2*)&sm.s.Vt[(cb+1)*72 + j0] = make_uint2((unsigned)s0.y | ((unsigned)s1.y<<16),
                                                           (unsigned)s2.y | ((unsigned)s3.y<<16));
            *(uint2*)&sm.s.Vt[(cb+2)*72 + j0] = make_uint2((unsigned)s0.z | ((unsigned)s1.z<<16),
                                                           (unsigned)s2.z | ((unsigned)s3.z<<16));
            *(uint2*)&sm.s.Vt[(cb+3)*72 + j0] = make_uint2((unsigned)s0.w | ((unsigned)s1.w<<16),
                                                           (unsigned)s2.w | ((unsigned)s3.w<<16));
        }
        __syncthreads();

        f32x16 sa[2];
#pragma unroll
        for (int ct = 0; ct < 2; ++ct) {
            f32x16 a2;
#pragma unroll
            for (int r = 0; r < 16; ++r) a2[r] = 0.f;
            const __hip_bfloat16* kb = &sm.s.K[(ct*32 + l31)*72 + 8*uh];
            a2 = __builtin_amdgcn_mfma_f32_32x32x16_bf16(*(const bf16x8*)(kb +  0), qf[0], a2, 0, 0, 0);
            a2 = __builtin_amdgcn_mfma_f32_32x32x16_bf16(*(const bf16x8*)(kb + 16), qf[1], a2, 0, 0, 0);
            a2 = __builtin_amdgcn_mfma_f32_32x32x16_bf16(*(const bf16x8*)(kb + 32), qf[2], a2, 0, 0, 0);
            a2 = __builtin_amdgcn_mfma_f32_32x32x16_bf16(*(const bf16x8*)(kb + 48), qf[3], a2, 0, 0, 0);
            sa[ct] = a2;
        }

        float p[32];
        float rs = 0.f;
#pragma unroll
        for (int ct = 0; ct < 2; ++ct)
#pragma unroll
            for (int r = 0; r < 16; ++r) {
                float e = __builtin_amdgcn_exp2f(sa[ct][r]);
                p[ct*16 + r] = e;
                rs += e;
            }
        rs += __shfl_xor(rs, 32);
        lrun += rs;

        bf16x8 bfr[4];
#pragma unroll
        for (int q = 0; q < 4; ++q) {
            int ct = q >> 1, b = (q & 1) << 3;
            unsigned A0 = pkbf_fast(p[ct*16+b+0], p[ct*16+b+1]);
            unsigned A1 = pkbf_fast(p[ct*16+b+2], p[ct*16+b+3]);
            unsigned B0 = pkbf_fast(p[ct*16+b+4], p[ct*16+b+5]);
            unsigned B1 = pkbf_fast(p[ct*16+b+6], p[ct*16+b+7]);
            unsigned xA0 = (unsigned)__shfl_xor((int)A0, 32);
            unsigned xA1 = (unsigned)__shfl_xor((int)A1, 32);
            unsigned xB0 = (unsigned)__shfl_xor((int)B0, 32);
            unsigned xB1 = (unsigned)__shfl_xor((int)B1, 32);
            union { uint4 i; bf16x8 v; } cv;
            cv.i = make_uint4(uh ? xB0 : A0, uh ? xB1 : A1,
                              uh ? B0 : xA0, uh ? B1 : xA1);
            bfr[q] = cv.v;
        }

#pragma unroll
        for (int c = 0; c < 2; ++c) {
            const __hip_bfloat16* vb = &sm.s.Vt[(c*32 + l31)*72 + 8*uh];
            oa[c] = __builtin_amdgcn_mfma_f32_32x32x16_bf16(*(const bf16x8*)(vb +  0), bfr[0], oa[c], 0, 0, 0);
            oa[c] = __builtin_amdgcn_mfma_f32_32x32x16_bf16(*(const bf16x8*)(vb + 16), bfr[1], oa[c], 0, 0, 0);
            oa[c] = __builtin_amdgcn_mfma_f32_32x32x16_bf16(*(const bf16x8*)(vb + 32), bfr[2], oa[c], 0, 0, 0);
            oa[c] = __builtin_amdgcn_mfma_f32_32x32x16_bf16(*(const bf16x8*)(vb + 48), bfr[3], oa[c], 0, 0, 0);
        }
    }

    __syncthreads();
    float invl = 1.0f / lrun;
    float* ob = sm.Ob[w];
#pragma unroll
    for (int c = 0; c < 2; ++c)
#pragma unroll
        for (int r = 0; r < 16; ++r) {
            int d = (r & 3) + ((r >> 2) << 3) + 4*uh + 32*c;
            ob[l31*68 + d] = oa[c][r] * invl;
        }
#pragma unroll
    for (int pp = 0; pp < 2; ++pp) {
        int qr = pp*16 + (lane >> 2);
        int dc = (lane & 3) << 4;
        size_t gi = ((size_t)(qt*128 + w*32 + qr)*ST + tt)*DM + h*64 + dc;
#pragma unroll
        for (int i = 0; i < 2; ++i) {
            uint4 rv = *(const uint4*)(R + gi + 8*i);
            *(uint4*)(O + gi + 8*i) = addpk(rv, &ob[qr*68 + dc + 8*i]);
        }
    }
}

// ================= temporal pooling + decoder ================================
__global__ __launch_bounds__(256) void final_k(const __hip_bfloat16* __restrict__ H,
        const float* __restrict__ HH, const float* __restrict__ dw,
        const float* __restrict__ db, float* __restrict__ out) {
    int n = blockIdx.x, d = threadIdx.x;
    int w = d >> 6, lane = d & 63;
    __shared__ float lam[ST];
    __shared__ float red[8];
    const float* hh = HH + (size_t)n*ST*DM;
    float4 qd = *(const float4*)(hh + 31*DM + lane*4);
#pragma unroll
    for (int i = 0; i < 8; ++i) {
        int t = w*8 + i;
        float4 h4 = *(const float4*)(hh + t*DM + lane*4);
        float s = wave_sum(h4.x*qd.x + h4.y*qd.y + h4.z*qd.z + h4.w*qd.w);
        if (lane == 0) lam[t] = s;
    }
    __syncthreads();
    float mx = -1e30f;
#pragma unroll
    for (int t = 0; t < ST; ++t) mx = fmaxf(mx, lam[t]);
    float sum = 0.f;
#pragma unroll
    for (int t = 0; t < ST; ++t) sum += __expf(lam[t]-mx);
    float acc = 0.f;
    const __hip_bfloat16* hrow = H + (size_t)n*ST*DM;
#pragma unroll
    for (int t = 0; t < ST; ++t)
        acc += __expf(lam[t]-mx) * __bfloat162float(hrow[t*DM + d]);
    acc /= sum;
    float p0 = wave_sum(acc * dw[2*d+0]);
    float p1 = wave_sum(acc * dw[2*d+1]);
    if (lane == 0) { red[w] = p0; red[4 + w] = p1; }
    __syncthreads();
    if (d == 0) {
        float r0 = red[0]+red[1]+red[2]+red[3] + db[0];
        float r1 = red[4]+red[5]+red[6]+red[7] + db[1];
        out[(size_t)n*2+0] = r0;           out[(size_t)n*2+1] = r1;
        out[2048 + (size_t)n*2+0] = r0;    out[2048 + (size_t)n*2+1] = r1;
        out[4096 + (size_t)n*2+0] = r0;    out[4096 + (size_t)n*2+1] = r1;
        if (n == 0) out[6144] = 0.f;
    }
}

extern "C" void kernel_launch(void* const* d_in, const int* in_sizes, int n_in,
                              void* d_out, int out_size, void* d_ws, size_t ws_size,
                              hipStream_t stream) {
    const float* x     = (const float*)d_in[0];
    const float* emb_w = (const float*)d_in[5];
    const float* emb_b = (const float*)d_in[6];
    const float* pe    = (const float*)d_in[7];
    const float* t_g1  = (const float*)d_in[11];
    const float* t_b1  = (const float*)d_in[12];
    const float* t_g2  = (const float*)d_in[13];
    const float* t_b2  = (const float*)d_in[14];
    const float* t_bb1 = (const float*)d_in[16];
    const float* t_bb2 = (const float*)d_in[18];
    const float* s_g1  = (const float*)d_in[22];
    const float* s_b1  = (const float*)d_in[23];
    const float* s_g2  = (const float*)d_in[24];
    const float* s_b2  = (const float*)d_in[25];
    const float* s_bb1 = (const float*)d_in[27];
    const float* s_bb2 = (const float*)d_in[29];
    const float* dec_w = (const float*)d_in[31];
    const float* dec_b = (const float*)d_in[32];
    float* out = (float*)d_out;

    // ---- workspace layout (~126 MB) ----
    float* F0 = (float*)d_ws;                       // 32 MB (hh, fp32)
    __hip_bfloat16* B0 = (__hip_bfloat16*)(F0 + SZ);// 16 MB each
    __hip_bfloat16* B1 = B0 + SZ;
    __hip_bfloat16* B2 = B1 + SZ;                   // B2,B3,B4 contiguous (fused QKV)
    __hip_bfloat16* B3 = B2 + SZ;
    __hip_bfloat16* B4 = B3 + SZ;
    __hip_bfloat16* WT  = B4 + SZ;                  // 11 x 256x256
    __hip_bfloat16* WTE = WT + (size_t)11*DM*DM;    // 256x192
    __hip_bfloat16* XB  = WTE + (size_t)DM*KE;      // 32768x192

    // ---- conversions ----
    cvtx_k<<<ROWS*KE/256, 256, 0, stream>>>(x, XB);
    WPack wp;
    const int widx[11] = {8, 9, 10, 15, 17, 19, 20, 21, 26, 28, 30};
    for (int i = 0; i < 11; ++i) {
        wp.s[i] = (const float*)d_in[widx[i]];
        wp.d[i] = WT + (size_t)i*DM*DM;
    }
    cvtw_k<<<dim3(4, 4, 11), 256, 0, stream>>>(wp);
    cvte_k<<<DM, 192, 0, stream>>>(emb_w, WTE);

    dim3 gg(ROWS/64, 2);                             // std gemm: 1024 blocks
    dim3 gq(ROWS/64, 6);                             // fused QKV: 3072 blocks
    __hip_bfloat16* WqT = WT;                        // Wq|Wk|Wv contiguous
    __hip_bfloat16* W1  = WT + (size_t)3*DM*DM;
    __hip_bfloat16* W2  = WT + (size_t)4*DM*DM;
    __hip_bfloat16* SWq = WT + (size_t)5*DM*DM;      // SWq|SWk|SWv contiguous
    __hip_bfloat16* SW1 = WT + (size_t)8*DM*DM;
    __hip_bfloat16* SW2 = WT + (size_t)9*DM*DM;
    __hip_bfloat16* WTA = WT + (size_t)10*DM*DM;

    // ---- embed + PE ----
    mgemm_k<<<gg, 256, 0, stream>>>(XB, KE, 3, WTE, KE, emb_b, pe, nullptr, nullptr, B0, 0, 0, 1.f, 0);
    // ---- TAttention block ----
    ln_k<<<ROWS/4, 256, 0, stream>>>(B0, t_g1, t_b1, B1);                 // B1 = xn
    mgemm_k<<<gq, 256, 0, stream>>>(B1, 256, 4, WqT, 256, nullptr, nullptr, nullptr, nullptr, B2, 0, 2, LOG2E, 1);
    attnT_k<<<NS, 256, 0, stream>>>(B2, B3, B4, B1, t_g2, t_b2, B1);      // B1 = LN(xn+att) = xt
    mgemm_k<<<gg, 256, 0, stream>>>(B1, 256, 4, W1, 256, t_bb1, nullptr, nullptr, nullptr, B2, 1, 0, 1.f, 0);
    mgemm_k<<<gg, 256, 0, stream>>>(B2, 256, 4, W2, 256, t_bb2, nullptr, B1, nullptr, B0, 0, 0, 1.f, 0);  // B0 = h1
    // ---- SAttention block ----
    ln_k<<<ROWS/4, 256, 0, stream>>>(B0, s_g1, s_b1, B1);                 // B1 = xn2
    mgemm_k<<<gq, 256, 0, stream>>>(B1, 256, 4, SWq, 256, nullptr, nullptr, nullptr, nullptr, B2, 0, 1, 0.125f*LOG2E, 1);
    attnS_k<<<dim3(32, 4, 8), 256, 0, stream>>>(B2, B3, B4, B1, B0);      // B0 = xn2+att
    ln_k<<<ROWS/4, 256, 0, stream>>>(B0, s_g2, s_b2, B1);                 // B1 = xt2
    mgemm_k<<<gg, 256, 0, stream>>>(B1, 256, 4, SW1, 256, s_bb1, nullptr, nullptr, nullptr, B2, 1, 0, 1.f, 0);
    mgemm_k<<<gg, 256, 0, stream>>>(B2, 256, 4, SW2, 256, s_bb2, nullptr, B1, nullptr, B0, 0, 0, 1.f, 0); // B0 = h2
    // ---- temporal attention + decoder ----
    mgemm_k<<<gg, 256, 0, stream>>>(B0, 256, 4, WTA, 256, nullptr, nullptr, nullptr, F0, nullptr, 0, 0, 1.f, 0);  // F0 = hh (fp32)
    final_k<<<NS, 256, 0, stream>>>(B0, F0, dec_w, dec_b, out);
}